// Round 2
// baseline (383.046 us; speedup 1.0000x reference)
//
#include <hip/hip_runtime.h>
#include <hip/hip_bf16.h>
#include <math.h>

// Problem constants (B, S, E, D) for SA_Layer_45603962749650
#define Bb 8
#define Ss 2048
#define Ee 512
#define Dd 512
#define QSPLIT 8

typedef __bf16 bf16x8 __attribute__((ext_vector_type(8)));
typedef __bf16 bf16x4 __attribute__((ext_vector_type(4)));
typedef float f32x4 __attribute__((ext_vector_type(4)));

// ---------------------------------------------------------------------------
// Pack f32 -> bf16 elementwise (x -> xb), n divisible by 4
// ---------------------------------------------------------------------------
__global__ void pack_bf16(const float* __restrict__ in, __bf16* __restrict__ out, int n) {
    const int i = (blockIdx.x * 256 + threadIdx.x) * 4;
    if (i < n) {
        const float4 v = *(const float4*)&in[i];
        bf16x4 o;
        o[0] = (__bf16)v.x; o[1] = (__bf16)v.y; o[2] = (__bf16)v.z; o[3] = (__bf16)v.w;
        *(bf16x4*)&out[i] = o;
    }
}

// ---------------------------------------------------------------------------
// Transpose 512x512: f32 in -> bf16 out  (Wq/Wk -> W^T so the GEMM is NT)
// ---------------------------------------------------------------------------
__global__ void transpose_w(const float* __restrict__ in, __bf16* __restrict__ out) {
    __shared__ float tile[32][33];
    const int x0 = blockIdx.x * 32;   // input col (d)
    const int y0 = blockIdx.y * 32;   // input row (e)
    for (int i = threadIdx.y; i < 32; i += 8)
        tile[i][threadIdx.x] = in[(size_t)(y0 + i) * 512 + (x0 + threadIdx.x)];
    __syncthreads();
    for (int i = threadIdx.y; i < 32; i += 8)
        out[(size_t)(x0 + i) * 512 + (y0 + threadIdx.x)] = (__bf16)tile[threadIdx.x][i];
}

// ---------------------------------------------------------------------------
// Transpose x: f32 [B][S][E] -> bf16 xT [B][E][S] (PV GEMM B-operand [e][k])
// ---------------------------------------------------------------------------
__global__ void transpose_x(const float* __restrict__ in, __bf16* __restrict__ out) {
    __shared__ float tile[32][33];
    const int b  = blockIdx.z;
    const int e0 = blockIdx.x * 32;
    const int s0 = blockIdx.y * 32;
    const float* ip = in + (size_t)b * Ss * Ee;
    __bf16* op = out + (size_t)b * Ee * Ss;
    for (int i = threadIdx.y; i < 32; i += 8)
        tile[i][threadIdx.x] = ip[(size_t)(s0 + i) * Ee + (e0 + threadIdx.x)];
    __syncthreads();
    for (int i = threadIdx.y; i < 32; i += 8)
        op[(size_t)(e0 + i) * Ss + (s0 + threadIdx.x)] = (__bf16)tile[threadIdx.x][i];
}

// ---------------------------------------------------------------------------
// Projection GEMM (NT): Out[m][n] = relu( sum_e X[m][e]*WT[n][e] + bias[n] )
// 128x128 tile, BK=32, 256 thr (4 waves, 2x2), each wave 4x4 of 16x16x32 MFMA
// Each thread stages rows r and r+64 (full 128x32 tile = 8KB per array).
// ---------------------------------------------------------------------------
__global__ __launch_bounds__(256, 2) void proj_kernel(
    const __bf16* __restrict__ X,    // [M, 512] bf16
    const __bf16* __restrict__ WT,   // [512, 512] bf16 (D-major)
    const float* __restrict__ bias,  // [512] f32
    __bf16* __restrict__ Out)        // [M, 512] bf16
{
    __shared__ __align__(16) ushort As[128 * 40];
    __shared__ __align__(16) ushort Bs[128 * 40];
    const int tid = threadIdx.x;
    const int wave = tid >> 6, lane = tid & 63, quad = lane >> 4, l16 = lane & 15;
    const int wm = (wave >> 1) * 64, wn = (wave & 1) * 64;
    const int m0 = blockIdx.y * 128, n0 = blockIdx.x * 128;
    const int r = tid >> 2, seg = (tid & 3) * 8;
    const int K = 512;

    f32x4 acc[4][4];
    f32x4 zero = {0.f, 0.f, 0.f, 0.f};
    for (int i = 0; i < 4; i++) for (int j = 0; j < 4; j++) acc[i][j] = zero;

    for (int k0 = 0; k0 < K; k0 += 32) {
        *(int4*)&As[r * 40 + seg]        = *(const int4*)&X[(size_t)(m0 + r) * K + k0 + seg];
        *(int4*)&As[(r + 64) * 40 + seg] = *(const int4*)&X[(size_t)(m0 + r + 64) * K + k0 + seg];
        *(int4*)&Bs[r * 40 + seg]        = *(const int4*)&WT[(size_t)(n0 + r) * K + k0 + seg];
        *(int4*)&Bs[(r + 64) * 40 + seg] = *(const int4*)&WT[(size_t)(n0 + r + 64) * K + k0 + seg];
        __syncthreads();
        bf16x8 af[4], bfr[4];
        for (int i = 0; i < 4; i++) af[i]  = *(bf16x8*)&As[(wm + i * 16 + l16) * 40 + quad * 8];
        for (int j = 0; j < 4; j++) bfr[j] = *(bf16x8*)&Bs[(wn + j * 16 + l16) * 40 + quad * 8];
        for (int i = 0; i < 4; i++)
            for (int j = 0; j < 4; j++)
                acc[i][j] = __builtin_amdgcn_mfma_f32_16x16x32_bf16(af[i], bfr[j], acc[i][j], 0, 0, 0);
        __syncthreads();
    }

    for (int i = 0; i < 4; i++) {
        const int row = m0 + wm + i * 16 + quad * 4;
        for (int j = 0; j < 4; j++) {
            const int col = n0 + wn + j * 16 + l16;
            const float bv = bias[col];
            for (int rr = 0; rr < 4; rr++) {
                float v = acc[i][j][rr] + bv;
                v = v > 0.f ? v : 0.f;
                Out[(size_t)(row + rr) * 512 + col] = (__bf16)v;
            }
        }
    }
}

// ---------------------------------------------------------------------------
// Scores GEMM (NT): Sc[b][q][k] = (1/sqrt(E)) * sum_d Q[q][d]*K[k][d] (f32 out)
// ---------------------------------------------------------------------------
__global__ __launch_bounds__(256, 2) void scores_kernel(
    const __bf16* __restrict__ Q,   // [B*S, D] bf16
    const __bf16* __restrict__ Km,  // [B*S, D] bf16
    float* __restrict__ Sc)         // [B, S, S] f32
{
    __shared__ __align__(16) ushort As[128 * 40];
    __shared__ __align__(16) ushort Bs[128 * 40];
    const int b = blockIdx.z;
    const __bf16* A  = Q  + (size_t)b * Ss * Dd;
    const __bf16* Bp = Km + (size_t)b * Ss * Dd;
    float* C = Sc + (size_t)b * Ss * Ss;

    const int tid = threadIdx.x;
    const int wave = tid >> 6, lane = tid & 63, quad = lane >> 4, l16 = lane & 15;
    const int wm = (wave >> 1) * 64, wn = (wave & 1) * 64;
    const int m0 = blockIdx.y * 128, n0 = blockIdx.x * 128;
    const int r = tid >> 2, seg = (tid & 3) * 8;
    const int K = Dd;
    const float scale = 0.044194173824159216f; // 1/sqrt(512)

    f32x4 acc[4][4];
    f32x4 zero = {0.f, 0.f, 0.f, 0.f};
    for (int i = 0; i < 4; i++) for (int j = 0; j < 4; j++) acc[i][j] = zero;

    for (int k0 = 0; k0 < K; k0 += 32) {
        *(int4*)&As[r * 40 + seg]        = *(const int4*)&A[(size_t)(m0 + r) * K + k0 + seg];
        *(int4*)&As[(r + 64) * 40 + seg] = *(const int4*)&A[(size_t)(m0 + r + 64) * K + k0 + seg];
        *(int4*)&Bs[r * 40 + seg]        = *(const int4*)&Bp[(size_t)(n0 + r) * K + k0 + seg];
        *(int4*)&Bs[(r + 64) * 40 + seg] = *(const int4*)&Bp[(size_t)(n0 + r + 64) * K + k0 + seg];
        __syncthreads();
        bf16x8 af[4], bfr[4];
        for (int i = 0; i < 4; i++) af[i]  = *(bf16x8*)&As[(wm + i * 16 + l16) * 40 + quad * 8];
        for (int j = 0; j < 4; j++) bfr[j] = *(bf16x8*)&Bs[(wn + j * 16 + l16) * 40 + quad * 8];
        for (int i = 0; i < 4; i++)
            for (int j = 0; j < 4; j++)
                acc[i][j] = __builtin_amdgcn_mfma_f32_16x16x32_bf16(af[i], bfr[j], acc[i][j], 0, 0, 0);
        __syncthreads();
    }

    for (int i = 0; i < 4; i++) {
        const int row = m0 + wm + i * 16 + quad * 4;
        for (int j = 0; j < 4; j++) {
            const int col = n0 + wn + j * 16 + l16;
            for (int rr = 0; rr < 4; rr++)
                C[(size_t)(row + rr) * Ss + col] = acc[i][j][rr] * scale;
        }
    }
}

// ---------------------------------------------------------------------------
// Column softmax stats, pass 1: partial (max, sumexp) over a q-chunk.
// softmax(dim=1) normalizes over q for each (b,k) column.
// ---------------------------------------------------------------------------
__global__ void stats_partial(const float* __restrict__ Sc,
                              float* __restrict__ Mp, float* __restrict__ Lp) {
    const int b = blockIdx.z, qy = blockIdx.y;
    const int k = blockIdx.x * 256 + threadIdx.x;
    const float* S0 = Sc + (size_t)b * Ss * Ss;
    const int q0 = qy * (Ss / QSPLIT);
    float m = -1e30f, l = 0.f;
    for (int q = q0; q < q0 + Ss / QSPLIT; ++q) {
        const float s = S0[(size_t)q * Ss + k];
        const float nm = fmaxf(m, s);
        l = l * __expf(m - nm) + __expf(s - nm);
        m = nm;
    }
    Mp[(size_t)(qy * Bb + b) * Ss + k] = m;
    Lp[(size_t)(qy * Bb + b) * Ss + k] = l;
}

// pass 2: combine QSPLIT partials -> Mf (col max) and Li (1/sumexp)
__global__ void stats_combine(const float* __restrict__ Mp, const float* __restrict__ Lp,
                              float* __restrict__ Mf, float* __restrict__ Li) {
    const int idx = blockIdx.x * 256 + threadIdx.x; // over B*S columns
    float m = -1e30f;
    for (int qy = 0; qy < QSPLIT; qy++) m = fmaxf(m, Mp[(size_t)qy * Bb * Ss + idx]);
    float l = 0.f;
    for (int qy = 0; qy < QSPLIT; qy++)
        l += Lp[(size_t)qy * Bb * Ss + idx] * __expf(Mp[(size_t)qy * Bb * Ss + idx] - m);
    Mf[idx] = m;
    Li[idx] = 1.0f / l;
}

// ---------------------------------------------------------------------------
// PV GEMM (NT) with fused softmax-normalize on A and fused residual:
// Out[b][q][e] = x[b][q][e] + sum_k exp(Sc[q][k]-Mf[k])*Li[k] * xT[b][e][k]
// ---------------------------------------------------------------------------
__global__ __launch_bounds__(256, 2) void pv_kernel(
    const float* __restrict__ Sc,    // [B,S,S] f32
    const float* __restrict__ Mf,    // [B,S] f32 (per key column)
    const float* __restrict__ Li,    // [B,S] f32 (1/sumexp per key column)
    const __bf16* __restrict__ XT,   // [B,E,S] bf16
    const float* __restrict__ X,     // [B,S,E] f32 (residual)
    float* __restrict__ Out)         // [B,S,E] f32
{
    __shared__ __align__(16) ushort As[128 * 40];
    __shared__ __align__(16) ushort Bs[128 * 40];
    const int b = blockIdx.z;
    const float* A   = Sc + (size_t)b * Ss * Ss;
    const __bf16* Bp = XT + (size_t)b * Ee * Ss;
    const float* Mv = Mf + (size_t)b * Ss;
    const float* Lv = Li + (size_t)b * Ss;

    const int tid = threadIdx.x;
    const int wave = tid >> 6, lane = tid & 63, quad = lane >> 4, l16 = lane & 15;
    const int wm = (wave >> 1) * 64, wn = (wave & 1) * 64;
    const int m0 = blockIdx.y * 128, n0 = blockIdx.x * 128;
    const int r = tid >> 2, seg = (tid & 3) * 8;
    const int K = Ss;

    f32x4 acc[4][4];
    f32x4 zero = {0.f, 0.f, 0.f, 0.f};
    for (int i = 0; i < 4; i++) for (int j = 0; j < 4; j++) acc[i][j] = zero;

    for (int k0 = 0; k0 < K; k0 += 32) {
        // softmax stats for this k-slab (same for both staged rows)
        const float4 ma = *(const float4*)&Mv[k0 + seg];
        const float4 mb = *(const float4*)&Mv[k0 + seg + 4];
        const float4 la = *(const float4*)&Lv[k0 + seg];
        const float4 lb = *(const float4*)&Lv[k0 + seg + 4];
        #pragma unroll
        for (int half = 0; half < 2; half++) {
            const int row = r + half * 64;
            const float4 sa = *(const float4*)&A[(size_t)(m0 + row) * Ss + k0 + seg];
            const float4 sb = *(const float4*)&A[(size_t)(m0 + row) * Ss + k0 + seg + 4];
            bf16x8 pv;
            pv[0] = (__bf16)(__expf(sa.x - ma.x) * la.x);
            pv[1] = (__bf16)(__expf(sa.y - ma.y) * la.y);
            pv[2] = (__bf16)(__expf(sa.z - ma.z) * la.z);
            pv[3] = (__bf16)(__expf(sa.w - ma.w) * la.w);
            pv[4] = (__bf16)(__expf(sb.x - mb.x) * lb.x);
            pv[5] = (__bf16)(__expf(sb.y - mb.y) * lb.y);
            pv[6] = (__bf16)(__expf(sb.z - mb.z) * lb.z);
            pv[7] = (__bf16)(__expf(sb.w - mb.w) * lb.w);
            *(bf16x8*)&As[row * 40 + seg] = pv;
        }
        *(int4*)&Bs[r * 40 + seg]        = *(const int4*)&Bp[(size_t)(n0 + r) * Ss + k0 + seg];
        *(int4*)&Bs[(r + 64) * 40 + seg] = *(const int4*)&Bp[(size_t)(n0 + r + 64) * Ss + k0 + seg];
        __syncthreads();
        bf16x8 af[4], bfr[4];
        for (int i = 0; i < 4; i++) af[i]  = *(bf16x8*)&As[(wm + i * 16 + l16) * 40 + quad * 8];
        for (int j = 0; j < 4; j++) bfr[j] = *(bf16x8*)&Bs[(wn + j * 16 + l16) * 40 + quad * 8];
        for (int i = 0; i < 4; i++)
            for (int j = 0; j < 4; j++)
                acc[i][j] = __builtin_amdgcn_mfma_f32_16x16x32_bf16(af[i], bfr[j], acc[i][j], 0, 0, 0);
        __syncthreads();
    }

    for (int i = 0; i < 4; i++) {
        const int row = m0 + wm + i * 16 + quad * 4;
        for (int j = 0; j < 4; j++) {
            const int col = n0 + wn + j * 16 + l16;
            for (int rr = 0; rr < 4; rr++) {
                const size_t idx = ((size_t)b * Ss + row + rr) * Ee + col;
                Out[idx] = X[idx] + acc[i][j][rr];
            }
        }
    }
}

// ---------------------------------------------------------------------------
extern "C" void kernel_launch(void* const* d_in, const int* in_sizes, int n_in,
                              void* d_out, int out_size, void* d_ws, size_t ws_size,
                              hipStream_t stream) {
    const float* x  = (const float*)d_in[0];
    const float* Wq = (const float*)d_in[1];
    const float* bq = (const float*)d_in[2];
    const float* Wk = (const float*)d_in[3];
    const float* bk = (const float*)d_in[4];
    float* out = (float*)d_out;

    char* ws = (char*)d_ws;
    size_t off = 0;
    auto alloc = [&](size_t bytes) -> void* {
        void* p = ws + off;
        off += (bytes + 255) & ~(size_t)255;
        return p;
    };
    float*  Sc  = (float*)alloc((size_t)Bb * Ss * Ss * 4);       // 128 MiB
    __bf16* xb  = (__bf16*)alloc((size_t)Bb * Ss * Ee * 2);      // 16 MiB
    __bf16* qb  = (__bf16*)alloc((size_t)Bb * Ss * Dd * 2);      // 16 MiB
    __bf16* kb  = (__bf16*)alloc((size_t)Bb * Ss * Dd * 2);      // 16 MiB
    __bf16* xT  = (__bf16*)alloc((size_t)Bb * Ee * Ss * 2);      // 16 MiB
    __bf16* WqT = (__bf16*)alloc((size_t)512 * 512 * 2);
    __bf16* WkT = (__bf16*)alloc((size_t)512 * 512 * 2);
    float*  Mp  = (float*)alloc((size_t)QSPLIT * Bb * Ss * 4);
    float*  Lp  = (float*)alloc((size_t)QSPLIT * Bb * Ss * 4);
    float*  Mf  = (float*)alloc((size_t)Bb * Ss * 4);
    float*  Li  = (float*)alloc((size_t)Bb * Ss * 4);
    if (off > ws_size) return;

    const int nx = Bb * Ss * Ee;
    pack_bf16<<<dim3(nx / (256 * 4)), 256, 0, stream>>>(x, xb, nx);
    transpose_w<<<dim3(16, 16), dim3(32, 8), 0, stream>>>(Wq, WqT);
    transpose_w<<<dim3(16, 16), dim3(32, 8), 0, stream>>>(Wk, WkT);
    transpose_x<<<dim3(16, 64, 8), dim3(32, 8), 0, stream>>>(x, xT);

    // q = relu(x Wq + bq), k = relu(x Wk + bk)   M=16384, N=512, K=512
    proj_kernel<<<dim3(4, 128), 256, 0, stream>>>(xb, WqT, bq, qb);
    proj_kernel<<<dim3(4, 128), 256, 0, stream>>>(xb, WkT, bk, kb);

    // scores = q k^T / sqrt(E)   per batch: 2048x2048, K=512
    scores_kernel<<<dim3(16, 16, 8), 256, 0, stream>>>(qb, kb, Sc);

    // column softmax stats over q (axis=1)
    stats_partial<<<dim3(Ss / 256, QSPLIT, Bb), 256, 0, stream>>>(Sc, Mp, Lp);
    stats_combine<<<dim3(Bb * Ss / 256), 256, 0, stream>>>(Mp, Lp, Mf, Li);

    // out = x + attn @ x   per batch: M=2048, N=512, K=2048
    pv_kernel<<<dim3(4, 16, 8), 256, 0, stream>>>(Sc, Mf, Li, xT, x, out);
}

// Round 3
// 325.644 us; speedup vs baseline: 1.1763x; 1.1763x over previous
//
#include <hip/hip_runtime.h>
#include <hip/hip_bf16.h>
#include <math.h>

// Problem constants (B, S, E, D) for SA_Layer_45603962749650
#define Bb 8
#define Ss 2048
#define Ee 512
#define Dd 512
#define QSPLIT 16   // one partial per 128-row scores tile

typedef __bf16 bf16x8 __attribute__((ext_vector_type(8)));
typedef __bf16 bf16x4 __attribute__((ext_vector_type(4)));
typedef __bf16 bf16x2 __attribute__((ext_vector_type(2)));
typedef float f32x4 __attribute__((ext_vector_type(4)));

// ---------------------------------------------------------------------------
// Pack f32 -> bf16 elementwise (x -> xb)
// ---------------------------------------------------------------------------
__global__ void pack_bf16(const float* __restrict__ in, __bf16* __restrict__ out, int n) {
    const int i = (blockIdx.x * 256 + threadIdx.x) * 4;
    if (i < n) {
        const float4 v = *(const float4*)&in[i];
        bf16x4 o;
        o[0] = (__bf16)v.x; o[1] = (__bf16)v.y; o[2] = (__bf16)v.z; o[3] = (__bf16)v.w;
        *(bf16x4*)&out[i] = o;
    }
}

// ---------------------------------------------------------------------------
// Transpose 512x512: f32 in -> bf16 out  (Wq/Wk -> W^T so the GEMM is NT)
// ---------------------------------------------------------------------------
__global__ void transpose_w(const float* __restrict__ in, __bf16* __restrict__ out) {
    __shared__ float tile[32][33];
    const int x0 = blockIdx.x * 32;
    const int y0 = blockIdx.y * 32;
    for (int i = threadIdx.y; i < 32; i += 8)
        tile[i][threadIdx.x] = in[(size_t)(y0 + i) * 512 + (x0 + threadIdx.x)];
    __syncthreads();
    for (int i = threadIdx.y; i < 32; i += 8)
        out[(size_t)(x0 + i) * 512 + (y0 + threadIdx.x)] = (__bf16)tile[threadIdx.x][i];
}

// ---------------------------------------------------------------------------
// Transpose x: f32 [B][S][E] -> bf16 xT [B][E][S]
// ---------------------------------------------------------------------------
__global__ void transpose_x(const float* __restrict__ in, __bf16* __restrict__ out) {
    __shared__ float tile[32][33];
    const int b  = blockIdx.z;
    const int e0 = blockIdx.x * 32;
    const int s0 = blockIdx.y * 32;
    const float* ip = in + (size_t)b * Ss * Ee;
    __bf16* op = out + (size_t)b * Ee * Ss;
    for (int i = threadIdx.y; i < 32; i += 8)
        tile[i][threadIdx.x] = ip[(size_t)(s0 + i) * Ee + (e0 + threadIdx.x)];
    __syncthreads();
    for (int i = threadIdx.y; i < 32; i += 8)
        op[(size_t)(e0 + i) * Ss + (s0 + threadIdx.x)] = (__bf16)tile[threadIdx.x][i];
}

// ---------------------------------------------------------------------------
// Projection GEMM (NT): Out = relu(X @ W + b), 128x128 tile, BK=32
// ---------------------------------------------------------------------------
__global__ __launch_bounds__(256, 4) void proj_kernel(
    const __bf16* __restrict__ X,    // [M, 512] bf16
    const __bf16* __restrict__ WT,   // [512, 512] bf16 (D-major)
    const float* __restrict__ bias,  // [512] f32
    __bf16* __restrict__ Out)        // [M, 512] bf16
{
    __shared__ __align__(16) ushort As[128 * 40];
    __shared__ __align__(16) ushort Bs[128 * 40];
    const int tid = threadIdx.x;
    const int wave = tid >> 6, lane = tid & 63, quad = lane >> 4, l16 = lane & 15;
    const int wm = (wave >> 1) * 64, wn = (wave & 1) * 64;
    const int m0 = blockIdx.y * 128, n0 = blockIdx.x * 128;
    const int r = tid >> 2, seg = (tid & 3) * 8;
    const int K = 512;

    f32x4 acc[4][4];
    f32x4 zero = {0.f, 0.f, 0.f, 0.f};
    for (int i = 0; i < 4; i++) for (int j = 0; j < 4; j++) acc[i][j] = zero;

    for (int k0 = 0; k0 < K; k0 += 32) {
        *(int4*)&As[r * 40 + seg]        = *(const int4*)&X[(size_t)(m0 + r) * K + k0 + seg];
        *(int4*)&As[(r + 64) * 40 + seg] = *(const int4*)&X[(size_t)(m0 + r + 64) * K + k0 + seg];
        *(int4*)&Bs[r * 40 + seg]        = *(const int4*)&WT[(size_t)(n0 + r) * K + k0 + seg];
        *(int4*)&Bs[(r + 64) * 40 + seg] = *(const int4*)&WT[(size_t)(n0 + r + 64) * K + k0 + seg];
        __syncthreads();
        bf16x8 af[4], bfr[4];
        for (int i = 0; i < 4; i++) af[i]  = *(bf16x8*)&As[(wm + i * 16 + l16) * 40 + quad * 8];
        for (int j = 0; j < 4; j++) bfr[j] = *(bf16x8*)&Bs[(wn + j * 16 + l16) * 40 + quad * 8];
        for (int i = 0; i < 4; i++)
            for (int j = 0; j < 4; j++)
                acc[i][j] = __builtin_amdgcn_mfma_f32_16x16x32_bf16(af[i], bfr[j], acc[i][j], 0, 0, 0);
        __syncthreads();
    }

    for (int i = 0; i < 4; i++) {
        const int row = m0 + wm + i * 16 + quad * 4;
        for (int j = 0; j < 4; j++) {
            const int col = n0 + wn + j * 16 + l16;
            const float bv = bias[col];
            for (int rr = 0; rr < 4; rr++) {
                float v = acc[i][j][rr] + bv;
                v = v > 0.f ? v : 0.f;
                Out[(size_t)(row + rr) * 512 + col] = (__bf16)v;
            }
        }
    }
}

// ---------------------------------------------------------------------------
// Scores GEMM (NT) + fused per-tile column-softmax partial stats.
// Sc[b][q][k] = (1/sqrt(E)) * sum_d Q[q][d]*K[k][d]  (f32 out)
// Partial (max, sumexp) over this tile's 128 q rows -> Mp/Lp[qy][b][k].
// ---------------------------------------------------------------------------
__global__ __launch_bounds__(256, 4) void scores_kernel(
    const __bf16* __restrict__ Q,   // [B*S, D] bf16
    const __bf16* __restrict__ Km,  // [B*S, D] bf16
    float* __restrict__ Sc,         // [B, S, S] f32
    float* __restrict__ Mp,         // [QSPLIT, B, S]
    float* __restrict__ Lp)         // [QSPLIT, B, S]
{
    __shared__ __align__(16) ushort As[128 * 40];
    __shared__ __align__(16) ushort Bs[128 * 40];
    const int b = blockIdx.z;
    const __bf16* A  = Q  + (size_t)b * Ss * Dd;
    const __bf16* Bp = Km + (size_t)b * Ss * Dd;
    float* C = Sc + (size_t)b * Ss * Ss;

    const int tid = threadIdx.x;
    const int wave = tid >> 6, lane = tid & 63, quad = lane >> 4, l16 = lane & 15;
    const int wm = (wave >> 1) * 64, wn = (wave & 1) * 64;
    const int m0 = blockIdx.y * 128, n0 = blockIdx.x * 128;
    const int r = tid >> 2, seg = (tid & 3) * 8;
    const int K = Dd;
    const float scale = 0.044194173824159216f; // 1/sqrt(512)

    f32x4 acc[4][4];
    f32x4 zero = {0.f, 0.f, 0.f, 0.f};
    for (int i = 0; i < 4; i++) for (int j = 0; j < 4; j++) acc[i][j] = zero;

    for (int k0 = 0; k0 < K; k0 += 32) {
        *(int4*)&As[r * 40 + seg]        = *(const int4*)&A[(size_t)(m0 + r) * K + k0 + seg];
        *(int4*)&As[(r + 64) * 40 + seg] = *(const int4*)&A[(size_t)(m0 + r + 64) * K + k0 + seg];
        *(int4*)&Bs[r * 40 + seg]        = *(const int4*)&Bp[(size_t)(n0 + r) * K + k0 + seg];
        *(int4*)&Bs[(r + 64) * 40 + seg] = *(const int4*)&Bp[(size_t)(n0 + r + 64) * K + k0 + seg];
        __syncthreads();
        bf16x8 af[4], bfr[4];
        for (int i = 0; i < 4; i++) af[i]  = *(bf16x8*)&As[(wm + i * 16 + l16) * 40 + quad * 8];
        for (int j = 0; j < 4; j++) bfr[j] = *(bf16x8*)&Bs[(wn + j * 16 + l16) * 40 + quad * 8];
        for (int i = 0; i < 4; i++)
            for (int j = 0; j < 4; j++)
                acc[i][j] = __builtin_amdgcn_mfma_f32_16x16x32_bf16(af[i], bfr[j], acc[i][j], 0, 0, 0);
        __syncthreads();
    }

    // C store
    for (int i = 0; i < 4; i++) {
        const int row = m0 + wm + i * 16 + quad * 4;
        for (int j = 0; j < 4; j++) {
            const int col = n0 + wn + j * 16 + l16;
            for (int rr = 0; rr < 4; rr++)
                C[(size_t)(row + rr) * Ss + col] = acc[i][j][rr] * scale;
        }
    }

    // ---- fused column-softmax partial stats over this tile's 128 rows ----
    float mj[4], lj[4];
    for (int j = 0; j < 4; j++) {
        float m = -1e30f;
        for (int i = 0; i < 4; i++)
            for (int rr = 0; rr < 4; rr++)
                m = fmaxf(m, acc[i][j][rr] * scale);
        float l = 0.f;
        for (int i = 0; i < 4; i++)
            for (int rr = 0; rr < 4; rr++)
                l += __expf(acc[i][j][rr] * scale - m);
        // combine across quads (lanes xor 16, 32 hold other rows of same col)
        for (int off = 16; off < 64; off <<= 1) {
            const float m2 = __shfl_xor(m, off);
            const float l2 = __shfl_xor(l, off);
            const float nm = fmaxf(m, m2);
            l = l * __expf(m - nm) + l2 * __expf(m2 - nm);
            m = nm;
        }
        mj[j] = m; lj[j] = l;
    }
    float* Ms = (float*)As;          // repurpose As (10 KB >= 2 KB needed)
    float* Ls = ((float*)As) + 256;
    const int half = wave >> 1;      // which 64-row half this wave covered
    if (quad == 0) {
        for (int j = 0; j < 4; j++) {
            Ms[half * 128 + wn + j * 16 + l16] = mj[j];
            Ls[half * 128 + wn + j * 16 + l16] = lj[j];
        }
    }
    __syncthreads();
    if (tid < 128) {
        float m = Ms[tid], l = Ls[tid];
        const float m2 = Ms[128 + tid], l2 = Ls[128 + tid];
        const float nm = fmaxf(m, m2);
        l = l * __expf(m - nm) + l2 * __expf(m2 - nm);
        const size_t o = ((size_t)(m0 >> 7) * Bb + b) * Ss + n0 + tid;
        Mp[o] = nm;
        Lp[o] = l;
    }
}

// combine QSPLIT partials -> Mf (col max) and Li (1/sumexp)
__global__ void stats_combine(const float* __restrict__ Mp, const float* __restrict__ Lp,
                              float* __restrict__ Mf, float* __restrict__ Li) {
    const int idx = blockIdx.x * 256 + threadIdx.x; // over B*S columns
    float m = -1e30f;
    for (int qy = 0; qy < QSPLIT; qy++) m = fmaxf(m, Mp[(size_t)qy * Bb * Ss + idx]);
    float l = 0.f;
    for (int qy = 0; qy < QSPLIT; qy++)
        l += Lp[(size_t)qy * Bb * Ss + idx] * __expf(Mp[(size_t)qy * Bb * Ss + idx] - m);
    Mf[idx] = m;
    Li[idx] = 1.0f / l;
}

// ---------------------------------------------------------------------------
// PV GEMM (NT), full-E n-extent so Sc is streamed exactly once.
// M-tile 32 (q), N 512 (e), K 2048. 512 threads = 8 waves, wave w -> e-cols
// [w*64, w*64+64). Fused softmax-normalize on A and fused residual.
// ---------------------------------------------------------------------------
__global__ __launch_bounds__(512, 4) void pv_kernel(
    const float* __restrict__ Sc,    // [B,S,S] f32 (scaled scores)
    const float* __restrict__ Mf,    // [B,S] per-key-column max
    const float* __restrict__ Li,    // [B,S] per-key-column 1/sumexp
    const __bf16* __restrict__ XT,   // [B,E,S] bf16
    const float* __restrict__ X,     // [B,S,E] f32 (residual)
    float* __restrict__ Out)         // [B,S,E] f32
{
    __shared__ __align__(16) ushort As[32 * 40];    // 2.5 KB
    __shared__ __align__(16) ushort Bs[512 * 40];   // 40 KB
    const int b  = blockIdx.y;
    const int m0 = blockIdx.x * 32;
    const float* A   = Sc + (size_t)b * Ss * Ss;
    const __bf16* Bp = XT + (size_t)b * Ee * Ss;
    const float* Mv  = Mf + (size_t)b * Ss;
    const float* Lv  = Li + (size_t)b * Ss;

    const int tid = threadIdx.x;
    const int wave = tid >> 6, lane = tid & 63, quad = lane >> 4, l16 = lane & 15;
    const int wn = wave * 64;
    const int ar = tid >> 4, aseg = (tid & 15) * 2;   // A stage: 32 rows x 16 thr
    const int br = tid >> 2, bseg = (tid & 3) * 8;    // B stage: 128 rows x 4 thr, x4 rounds

    f32x4 acc[2][4];
    f32x4 zero = {0.f, 0.f, 0.f, 0.f};
    for (int i = 0; i < 2; i++) for (int j = 0; j < 4; j++) acc[i][j] = zero;

    for (int k0 = 0; k0 < Ss; k0 += 32) {
        // A staging: f32 scores -> normalized attn bf16
        const float2 s  = *(const float2*)&A[(size_t)(m0 + ar) * Ss + k0 + aseg];
        const float2 mm = *(const float2*)&Mv[k0 + aseg];
        const float2 ll = *(const float2*)&Lv[k0 + aseg];
        bf16x2 pv;
        pv[0] = (__bf16)(__expf(s.x - mm.x) * ll.x);
        pv[1] = (__bf16)(__expf(s.y - mm.y) * ll.y);
        *(bf16x2*)&As[ar * 40 + aseg] = pv;
        // B staging: xT slab 512 x 32
        #pragma unroll
        for (int i = 0; i < 4; i++)
            *(int4*)&Bs[(br + i * 128) * 40 + bseg] =
                *(const int4*)&Bp[(size_t)(br + i * 128) * Ss + k0 + bseg];
        __syncthreads();
        bf16x8 af[2], bfr[4];
        for (int i = 0; i < 2; i++) af[i]  = *(bf16x8*)&As[(i * 16 + l16) * 40 + quad * 8];
        for (int j = 0; j < 4; j++) bfr[j] = *(bf16x8*)&Bs[(wn + j * 16 + l16) * 40 + quad * 8];
        for (int i = 0; i < 2; i++)
            for (int j = 0; j < 4; j++)
                acc[i][j] = __builtin_amdgcn_mfma_f32_16x16x32_bf16(af[i], bfr[j], acc[i][j], 0, 0, 0);
        __syncthreads();
    }

    for (int i = 0; i < 2; i++) {
        const int row = m0 + i * 16 + quad * 4;
        for (int j = 0; j < 4; j++) {
            const int col = wn + j * 16 + l16;
            for (int rr = 0; rr < 4; rr++) {
                const size_t idx = ((size_t)b * Ss + row + rr) * Ee + col;
                Out[idx] = X[idx] + acc[i][j][rr];
            }
        }
    }
}

// ---------------------------------------------------------------------------
extern "C" void kernel_launch(void* const* d_in, const int* in_sizes, int n_in,
                              void* d_out, int out_size, void* d_ws, size_t ws_size,
                              hipStream_t stream) {
    const float* x  = (const float*)d_in[0];
    const float* Wq = (const float*)d_in[1];
    const float* bq = (const float*)d_in[2];
    const float* Wk = (const float*)d_in[3];
    const float* bk = (const float*)d_in[4];
    float* out = (float*)d_out;

    char* ws = (char*)d_ws;
    size_t off = 0;
    auto alloc = [&](size_t bytes) -> void* {
        void* p = ws + off;
        off += (bytes + 255) & ~(size_t)255;
        return p;
    };
    float*  Sc  = (float*)alloc((size_t)Bb * Ss * Ss * 4);       // 128 MiB
    __bf16* xb  = (__bf16*)alloc((size_t)Bb * Ss * Ee * 2);      // 16 MiB
    __bf16* qb  = (__bf16*)alloc((size_t)Bb * Ss * Dd * 2);      // 16 MiB
    __bf16* kb  = (__bf16*)alloc((size_t)Bb * Ss * Dd * 2);      // 16 MiB
    __bf16* xT  = (__bf16*)alloc((size_t)Bb * Ee * Ss * 2);      // 16 MiB
    __bf16* WqT = (__bf16*)alloc((size_t)512 * 512 * 2);
    __bf16* WkT = (__bf16*)alloc((size_t)512 * 512 * 2);
    float*  Mp  = (float*)alloc((size_t)QSPLIT * Bb * Ss * 4);   // 1 MiB
    float*  Lp  = (float*)alloc((size_t)QSPLIT * Bb * Ss * 4);   // 1 MiB
    float*  Mf  = (float*)alloc((size_t)Bb * Ss * 4);
    float*  Li  = (float*)alloc((size_t)Bb * Ss * 4);
    if (off > ws_size) return;

    const int nx = Bb * Ss * Ee;
    pack_bf16<<<dim3(nx / (256 * 4)), 256, 0, stream>>>(x, xb, nx);
    transpose_w<<<dim3(16, 16), dim3(32, 8), 0, stream>>>(Wq, WqT);
    transpose_w<<<dim3(16, 16), dim3(32, 8), 0, stream>>>(Wk, WkT);
    transpose_x<<<dim3(16, 64, 8), dim3(32, 8), 0, stream>>>(x, xT);

    // q = relu(x Wq + bq), k = relu(x Wk + bk)   M=16384, N=512, K=512
    proj_kernel<<<dim3(4, 128), 256, 0, stream>>>(xb, WqT, bq, qb);
    proj_kernel<<<dim3(4, 128), 256, 0, stream>>>(xb, WkT, bk, kb);

    // scores = q k^T / sqrt(E) + fused per-tile column stats
    scores_kernel<<<dim3(16, 16, 8), 256, 0, stream>>>(qb, kb, Sc, Mp, Lp);
    stats_combine<<<dim3(Bb * Ss / 256), 256, 0, stream>>>(Mp, Lp, Mf, Li);

    // out = x + attn @ x   per batch: M=2048 (32/block), N=512, K=2048
    pv_kernel<<<dim3(64, 8), 512, 0, stream>>>(Sc, Mf, Li, xT, x, out);
}

// Round 4
// 264.916 us; speedup vs baseline: 1.4459x; 1.2292x over previous
//
#include <hip/hip_runtime.h>
#include <hip/hip_bf16.h>
#include <math.h>

// Problem constants (B, S, E, D) for SA_Layer_45603962749650
#define Bb 8
#define Ss 2048
#define Ee 512
#define Dd 512
#define QSPLIT 16   // one partial per 128-row scores tile

typedef __bf16 bf16x8 __attribute__((ext_vector_type(8)));
typedef __bf16 bf16x4 __attribute__((ext_vector_type(4)));
typedef float f32x4 __attribute__((ext_vector_type(4)));

// ---------------------------------------------------------------------------
// prep_x: one pass over x. Writes xb = bf16(x) [B,S,E] and xT = bf16(x^T) [B,E,S]
// ---------------------------------------------------------------------------
__global__ void prep_x(const float* __restrict__ in, __bf16* __restrict__ xb,
                       __bf16* __restrict__ xT) {
    __shared__ float tile[32][33];
    const int b  = blockIdx.z;
    const int e0 = blockIdx.x * 32;
    const int s0 = blockIdx.y * 32;
    const float* ip = in + (size_t)b * Ss * Ee;
    __bf16* xbp = xb + (size_t)b * Ss * Ee;
    __bf16* xTp = xT + (size_t)b * Ee * Ss;
    for (int i = threadIdx.y; i < 32; i += 8) {
        const float v = ip[(size_t)(s0 + i) * Ee + e0 + threadIdx.x];
        tile[i][threadIdx.x] = v;
        xbp[(size_t)(s0 + i) * Ee + e0 + threadIdx.x] = (__bf16)v;
    }
    __syncthreads();
    for (int i = threadIdx.y; i < 32; i += 8)
        xTp[(size_t)(e0 + i) * Ss + s0 + threadIdx.x] = (__bf16)tile[threadIdx.x][i];
}

// ---------------------------------------------------------------------------
// Transpose 512x512: f32 in -> bf16 out. blockIdx.z selects Wq/Wk.
// ---------------------------------------------------------------------------
__global__ void transpose_w(const float* __restrict__ Wq, const float* __restrict__ Wk,
                            __bf16* __restrict__ WqT, __bf16* __restrict__ WkT) {
    __shared__ float tile[32][33];
    const float* in = blockIdx.z ? Wk : Wq;
    __bf16* out = blockIdx.z ? WkT : WqT;
    const int x0 = blockIdx.x * 32;
    const int y0 = blockIdx.y * 32;
    for (int i = threadIdx.y; i < 32; i += 8)
        tile[i][threadIdx.x] = in[(size_t)(y0 + i) * 512 + (x0 + threadIdx.x)];
    __syncthreads();
    for (int i = threadIdx.y; i < 32; i += 8)
        out[(size_t)(x0 + i) * 512 + (y0 + threadIdx.x)] = (__bf16)tile[threadIdx.x][i];
}

// ---------------------------------------------------------------------------
// Projection GEMM (NT): Out = relu(X @ W + b), 128x128 tile, BK=32.
// blockIdx.z selects (WqT,bq,qb) vs (WkT,bk,kb).
// ---------------------------------------------------------------------------
__global__ __launch_bounds__(256, 4) void proj_kernel(
    const __bf16* __restrict__ X,
    const __bf16* __restrict__ WqT, const __bf16* __restrict__ WkT,
    const float* __restrict__ bq, const float* __restrict__ bk,
    __bf16* __restrict__ qb, __bf16* __restrict__ kb)
{
    __shared__ __align__(16) ushort As[128 * 40];
    __shared__ __align__(16) ushort Bs[128 * 40];
    const __bf16* WT  = blockIdx.z ? WkT : WqT;
    const float* bias = blockIdx.z ? bk : bq;
    __bf16* Out       = blockIdx.z ? kb : qb;

    const int tid = threadIdx.x;
    const int wave = tid >> 6, lane = tid & 63, quad = lane >> 4, l16 = lane & 15;
    const int wm = (wave >> 1) * 64, wn = (wave & 1) * 64;
    const int m0 = blockIdx.y * 128, n0 = blockIdx.x * 128;
    const int r = tid >> 2, seg = (tid & 3) * 8;
    const int K = 512;

    f32x4 acc[4][4];
    f32x4 zero = {0.f, 0.f, 0.f, 0.f};
    for (int i = 0; i < 4; i++) for (int j = 0; j < 4; j++) acc[i][j] = zero;

    for (int k0 = 0; k0 < K; k0 += 32) {
        *(int4*)&As[r * 40 + seg]        = *(const int4*)&X[(size_t)(m0 + r) * K + k0 + seg];
        *(int4*)&As[(r + 64) * 40 + seg] = *(const int4*)&X[(size_t)(m0 + r + 64) * K + k0 + seg];
        *(int4*)&Bs[r * 40 + seg]        = *(const int4*)&WT[(size_t)(n0 + r) * K + k0 + seg];
        *(int4*)&Bs[(r + 64) * 40 + seg] = *(const int4*)&WT[(size_t)(n0 + r + 64) * K + k0 + seg];
        __syncthreads();
        bf16x8 af[4], bfr[4];
        for (int i = 0; i < 4; i++) af[i]  = *(bf16x8*)&As[(wm + i * 16 + l16) * 40 + quad * 8];
        for (int j = 0; j < 4; j++) bfr[j] = *(bf16x8*)&Bs[(wn + j * 16 + l16) * 40 + quad * 8];
        for (int i = 0; i < 4; i++)
            for (int j = 0; j < 4; j++)
                acc[i][j] = __builtin_amdgcn_mfma_f32_16x16x32_bf16(af[i], bfr[j], acc[i][j], 0, 0, 0);
        __syncthreads();
    }

    for (int i = 0; i < 4; i++) {
        const int row = m0 + wm + i * 16 + quad * 4;
        for (int j = 0; j < 4; j++) {
            const int col = n0 + wn + j * 16 + l16;
            const float bv = bias[col];
            for (int rr = 0; rr < 4; rr++) {
                float v = acc[i][j][rr] + bv;
                v = v > 0.f ? v : 0.f;
                Out[(size_t)(row + rr) * 512 + col] = (__bf16)v;
            }
        }
    }
}

// ---------------------------------------------------------------------------
// Scores GEMM (NT) + fused column-softmax tile stats + bf16 P output:
//   sv = q.k/sqrt(E);  m_tile[k] = max over this tile's 128 q rows
//   P[q][k] = bf16(exp(sv - m_tile[k]))        (in (0,1] -> bf16-safe)
//   Mp[qy][b][k] = m_tile (scaled), Lp = sum_q exp(sv - m_tile)
// ---------------------------------------------------------------------------
__global__ __launch_bounds__(256, 4) void scores_kernel(
    const __bf16* __restrict__ Q,   // [B*S, D] bf16
    const __bf16* __restrict__ Km,  // [B*S, D] bf16
    __bf16* __restrict__ P,         // [B, S, S] bf16
    float* __restrict__ Mp,         // [QSPLIT, B, S]
    float* __restrict__ Lp)         // [QSPLIT, B, S]
{
    __shared__ __align__(16) ushort As[128 * 40];
    __shared__ __align__(16) ushort Bs[128 * 40];
    const int b = blockIdx.z;
    const __bf16* A  = Q  + (size_t)b * Ss * Dd;
    const __bf16* Bp = Km + (size_t)b * Ss * Dd;
    __bf16* C = P + (size_t)b * Ss * Ss;

    const int tid = threadIdx.x;
    const int wave = tid >> 6, lane = tid & 63, quad = lane >> 4, l16 = lane & 15;
    const int wm = (wave >> 1) * 64, wn = (wave & 1) * 64;
    const int m0 = blockIdx.y * 128, n0 = blockIdx.x * 128;
    const int r = tid >> 2, seg = (tid & 3) * 8;
    const int K = Dd;
    const float scale = 0.044194173824159216f; // 1/sqrt(512)

    f32x4 acc[4][4];
    f32x4 zero = {0.f, 0.f, 0.f, 0.f};
    for (int i = 0; i < 4; i++) for (int j = 0; j < 4; j++) acc[i][j] = zero;

    for (int k0 = 0; k0 < K; k0 += 32) {
        *(int4*)&As[r * 40 + seg]        = *(const int4*)&A[(size_t)(m0 + r) * K + k0 + seg];
        *(int4*)&As[(r + 64) * 40 + seg] = *(const int4*)&A[(size_t)(m0 + r + 64) * K + k0 + seg];
        *(int4*)&Bs[r * 40 + seg]        = *(const int4*)&Bp[(size_t)(n0 + r) * K + k0 + seg];
        *(int4*)&Bs[(r + 64) * 40 + seg] = *(const int4*)&Bp[(size_t)(n0 + r + 64) * K + k0 + seg];
        __syncthreads();
        bf16x8 af[4], bfr[4];
        for (int i = 0; i < 4; i++) af[i]  = *(bf16x8*)&As[(wm + i * 16 + l16) * 40 + quad * 8];
        for (int j = 0; j < 4; j++) bfr[j] = *(bf16x8*)&Bs[(wn + j * 16 + l16) * 40 + quad * 8];
        for (int i = 0; i < 4; i++)
            for (int j = 0; j < 4; j++)
                acc[i][j] = __builtin_amdgcn_mfma_f32_16x16x32_bf16(af[i], bfr[j], acc[i][j], 0, 0, 0);
        __syncthreads();
    }

    // ---- tile column max (unscaled domain; scale > 0 commutes with max) ----
    float* Ms = (float*)As;          // 256 f32
    float* Ls = ((float*)As) + 256;  // 256 f32
    const int half = wave >> 1;
    float mj[4];
    for (int j = 0; j < 4; j++) {
        float m = -1e30f;
        for (int i = 0; i < 4; i++)
            for (int rr = 0; rr < 4; rr++)
                m = fmaxf(m, acc[i][j][rr]);
        m = fmaxf(m, __shfl_xor(m, 16));
        m = fmaxf(m, __shfl_xor(m, 32));
        mj[j] = m;  // per-64-row-half col max
    }
    if (quad == 0)
        for (int j = 0; j < 4; j++) Ms[half * 128 + wn + j * 16 + l16] = mj[j];
    __syncthreads();
    float mt[4];
    for (int j = 0; j < 4; j++) {
        const int c = wn + j * 16 + l16;
        mt[j] = fmaxf(Ms[c], Ms[128 + c]);
    }
    // ---- exp + P store (bf16) + column sum ----
    float lj[4];
    for (int j = 0; j < 4; j++) {
        const int col = n0 + wn + j * 16 + l16;
        float l = 0.f;
        for (int i = 0; i < 4; i++) {
            const int row = m0 + wm + i * 16 + quad * 4;
            for (int rr = 0; rr < 4; rr++) {
                const float e = __expf((acc[i][j][rr] - mt[j]) * scale);
                C[(size_t)(row + rr) * Ss + col] = (__bf16)e;
                l += e;
            }
        }
        l += __shfl_xor(l, 16);
        l += __shfl_xor(l, 32);
        lj[j] = l;
    }
    if (quad == 0)
        for (int j = 0; j < 4; j++) Ls[half * 128 + wn + j * 16 + l16] = lj[j];
    __syncthreads();
    if (tid < 128) {
        const size_t o = ((size_t)blockIdx.y * Bb + b) * Ss + n0 + tid;
        Mp[o] = fmaxf(Ms[tid], Ms[128 + tid]) * scale;  // scaled tile max
        Lp[o] = Ls[tid] + Ls[128 + tid];                // both halves used mt
    }
}

// combine QSPLIT tile partials -> Mf (col max, scaled) and Li (1/sumexp)
__global__ void stats_combine(const float* __restrict__ Mp, const float* __restrict__ Lp,
                              float* __restrict__ Mf, float* __restrict__ Li) {
    const int idx = blockIdx.x * 256 + threadIdx.x; // over B*S columns
    float m = -1e30f;
    for (int qy = 0; qy < QSPLIT; qy++) m = fmaxf(m, Mp[(size_t)qy * Bb * Ss + idx]);
    float l = 0.f;
    for (int qy = 0; qy < QSPLIT; qy++)
        l += Lp[(size_t)qy * Bb * Ss + idx] * __expf(Mp[(size_t)qy * Bb * Ss + idx] - m);
    Mf[idx] = m;
    Li[idx] = 1.0f / l;
}

// ---------------------------------------------------------------------------
// PV GEMM (NT), 128x128 m97-style. attn[q][k] = P[q][k] * corr[k] with
// corr[k] = exp(Mp[qy][k]-Mf[k])*Li[k] precomputed per block into LDS.
// Epilogue fuses the residual: Out = X + attn @ x.
// ---------------------------------------------------------------------------
__global__ __launch_bounds__(256, 4) void pv_kernel(
    const __bf16* __restrict__ P,    // [B,S,S] bf16 tile-shifted exp scores
    const float* __restrict__ Mp,    // [QSPLIT,B,S]
    const float* __restrict__ Mf,    // [B,S]
    const float* __restrict__ Li,    // [B,S]
    const __bf16* __restrict__ XT,   // [B,E,S] bf16
    const float* __restrict__ X,     // [B,S,E] f32 (residual)
    float* __restrict__ Out)         // [B,S,E] f32
{
    __shared__ __align__(16) ushort As[128 * 40];
    __shared__ __align__(16) ushort Bs[128 * 40];
    __shared__ float corr[Ss];       // 8 KB
    const int b = blockIdx.z;
    const int m0 = blockIdx.y * 128, n0 = blockIdx.x * 128;
    const int qy = blockIdx.y;       // pv M-tile == scores M-tile (128)
    const __bf16* A  = P  + (size_t)b * Ss * Ss;
    const __bf16* Bp = XT + (size_t)b * Ee * Ss;

    const int tid = threadIdx.x;
    const int wave = tid >> 6, lane = tid & 63, quad = lane >> 4, l16 = lane & 15;
    const int wm = (wave >> 1) * 64, wn = (wave & 1) * 64;
    const int r = tid >> 2, seg = (tid & 3) * 8;

    // per-block correction table over the full K extent
    for (int k = tid; k < Ss; k += 256) {
        const float mp = Mp[((size_t)qy * Bb + b) * Ss + k];
        corr[k] = __expf(mp - Mf[(size_t)b * Ss + k]) * Li[(size_t)b * Ss + k];
    }
    __syncthreads();

    f32x4 acc[4][4];
    f32x4 zero = {0.f, 0.f, 0.f, 0.f};
    for (int i = 0; i < 4; i++) for (int j = 0; j < 4; j++) acc[i][j] = zero;

    for (int k0 = 0; k0 < Ss; k0 += 32) {
        float cv[8];
        #pragma unroll
        for (int t = 0; t < 8; t++) cv[t] = corr[k0 + seg + t];
        #pragma unroll
        for (int half = 0; half < 2; half++) {
            const int row = r + half * 64;
            const bf16x8 p = *(const bf16x8*)&A[(size_t)(m0 + row) * Ss + k0 + seg];
            bf16x8 o;
            #pragma unroll
            for (int t = 0; t < 8; t++) o[t] = (__bf16)((float)p[t] * cv[t]);
            *(bf16x8*)&As[row * 40 + seg] = o;
        }
        *(int4*)&Bs[r * 40 + seg]        = *(const int4*)&Bp[(size_t)(n0 + r) * Ss + k0 + seg];
        *(int4*)&Bs[(r + 64) * 40 + seg] = *(const int4*)&Bp[(size_t)(n0 + r + 64) * Ss + k0 + seg];
        __syncthreads();
        bf16x8 af[4], bfr[4];
        for (int i = 0; i < 4; i++) af[i]  = *(bf16x8*)&As[(wm + i * 16 + l16) * 40 + quad * 8];
        for (int j = 0; j < 4; j++) bfr[j] = *(bf16x8*)&Bs[(wn + j * 16 + l16) * 40 + quad * 8];
        for (int i = 0; i < 4; i++)
            for (int j = 0; j < 4; j++)
                acc[i][j] = __builtin_amdgcn_mfma_f32_16x16x32_bf16(af[i], bfr[j], acc[i][j], 0, 0, 0);
        __syncthreads();
    }

    for (int i = 0; i < 4; i++) {
        const int row = m0 + wm + i * 16 + quad * 4;
        for (int j = 0; j < 4; j++) {
            const int col = n0 + wn + j * 16 + l16;
            for (int rr = 0; rr < 4; rr++) {
                const size_t idx = ((size_t)b * Ss + row + rr) * Ee + col;
                Out[idx] = X[idx] + acc[i][j][rr];
            }
        }
    }
}

// ---------------------------------------------------------------------------
extern "C" void kernel_launch(void* const* d_in, const int* in_sizes, int n_in,
                              void* d_out, int out_size, void* d_ws, size_t ws_size,
                              hipStream_t stream) {
    const float* x  = (const float*)d_in[0];
    const float* Wq = (const float*)d_in[1];
    const float* bq = (const float*)d_in[2];
    const float* Wk = (const float*)d_in[3];
    const float* bk = (const float*)d_in[4];
    float* out = (float*)d_out;

    char* ws = (char*)d_ws;
    size_t off = 0;
    auto alloc = [&](size_t bytes) -> void* {
        void* p = ws + off;
        off += (bytes + 255) & ~(size_t)255;
        return p;
    };
    __bf16* P   = (__bf16*)alloc((size_t)Bb * Ss * Ss * 2);      // 64 MiB
    __bf16* xb  = (__bf16*)alloc((size_t)Bb * Ss * Ee * 2);      // 16 MiB
    __bf16* qb  = (__bf16*)alloc((size_t)Bb * Ss * Dd * 2);      // 16 MiB
    __bf16* kb  = (__bf16*)alloc((size_t)Bb * Ss * Dd * 2);      // 16 MiB
    __bf16* xT  = (__bf16*)alloc((size_t)Bb * Ee * Ss * 2);      // 16 MiB
    __bf16* WqT = (__bf16*)alloc((size_t)512 * 512 * 2);
    __bf16* WkT = (__bf16*)alloc((size_t)512 * 512 * 2);
    float*  Mp  = (float*)alloc((size_t)QSPLIT * Bb * Ss * 4);   // 1 MiB
    float*  Lp  = (float*)alloc((size_t)QSPLIT * Bb * Ss * 4);   // 1 MiB
    float*  Mf  = (float*)alloc((size_t)Bb * Ss * 4);
    float*  Li  = (float*)alloc((size_t)Bb * Ss * 4);
    if (off > ws_size) return;

    prep_x<<<dim3(16, 64, 8), dim3(32, 8), 0, stream>>>(x, xb, xT);
    transpose_w<<<dim3(16, 16, 2), dim3(32, 8), 0, stream>>>(Wq, Wk, WqT, WkT);

    // q = relu(x Wq + bq), k = relu(x Wk + bk)   M=16384, N=512, K=512
    proj_kernel<<<dim3(4, 128, 2), 256, 0, stream>>>(xb, WqT, WkT, bq, bk, qb, kb);

    // P = exp(q k^T / sqrt(E) - m_tile) bf16 + tile stats
    scores_kernel<<<dim3(16, 16, 8), 256, 0, stream>>>(qb, kb, P, Mp, Lp);
    stats_combine<<<dim3(Bb * Ss / 256), 256, 0, stream>>>(Mp, Lp, Mf, Li);

    // out = x + attn @ x   per batch: M=2048, N=512, K=2048
    pv_kernel<<<dim3(4, 16, 8), 256, 0, stream>>>(P, Mp, Mf, Li, xT, x, out);
}

// Round 5
// 239.788 us; speedup vs baseline: 1.5974x; 1.1048x over previous
//
#include <hip/hip_runtime.h>
#include <hip/hip_bf16.h>
#include <math.h>

// Problem constants (B, S, E, D) for SA_Layer_45603962749650
#define Bb 8
#define Ss 2048
#define Ee 512
#define Dd 512
#define QSPLIT 16   // one partial per 128-row scores tile

typedef __bf16 bf16x8 __attribute__((ext_vector_type(8)));
typedef __bf16 bf16x4 __attribute__((ext_vector_type(4)));
typedef float f32x4 __attribute__((ext_vector_type(4)));

// ---------------------------------------------------------------------------
// Async-stage one 128x32 bf16 tile into swizzled LDS [128][32] (no padding).
// Chunk q (16B) of row r lives at physical chunk q ^ ((r>>1)&3).
// Wave w issues 2 global_load_lds; LDS side is wave-uniform base + lane*16.
// ---------------------------------------------------------------------------
__device__ __forceinline__ void stage_async(ushort* lds, const __bf16* gbase,
                                            int ldg, int wave, int lane) {
#pragma unroll
    for (int t = 0; t < 2; ++t) {
        const int idx = wave * 2 + t;               // 16-row chunk 0..7
        const int row = idx * 16 + (lane >> 2);
        const int q8  = (((lane & 3) ^ ((lane >> 3) & 3)) * 8); // data chunk for this slot
        __builtin_amdgcn_global_load_lds(
            (const __attribute__((address_space(1))) void*)(gbase + (size_t)row * ldg + q8),
            (__attribute__((address_space(3))) void*)(lds + idx * 512),
            16, 0, 0);
    }
}

// ---------------------------------------------------------------------------
// prep_x: one pass over x. Writes xb = bf16(x) [B,S,E] and xT = bf16(x^T) [B,E,S]
// ---------------------------------------------------------------------------
__global__ void prep_x(const float* __restrict__ in, __bf16* __restrict__ xb,
                       __bf16* __restrict__ xT) {
    __shared__ float tile[32][33];
    const int b  = blockIdx.z;
    const int e0 = blockIdx.x * 32;
    const int s0 = blockIdx.y * 32;
    const float* ip = in + (size_t)b * Ss * Ee;
    __bf16* xbp = xb + (size_t)b * Ss * Ee;
    __bf16* xTp = xT + (size_t)b * Ee * Ss;
    for (int i = threadIdx.y; i < 32; i += 8) {
        const float v = ip[(size_t)(s0 + i) * Ee + e0 + threadIdx.x];
        tile[i][threadIdx.x] = v;
        xbp[(size_t)(s0 + i) * Ee + e0 + threadIdx.x] = (__bf16)v;
    }
    __syncthreads();
    for (int i = threadIdx.y; i < 32; i += 8)
        xTp[(size_t)(e0 + i) * Ss + s0 + threadIdx.x] = (__bf16)tile[threadIdx.x][i];
}

// ---------------------------------------------------------------------------
// Transpose 512x512: f32 in -> bf16 out. blockIdx.z selects Wq/Wk.
// ---------------------------------------------------------------------------
__global__ void transpose_w(const float* __restrict__ Wq, const float* __restrict__ Wk,
                            __bf16* __restrict__ WqT, __bf16* __restrict__ WkT) {
    __shared__ float tile[32][33];
    const float* in = blockIdx.z ? Wk : Wq;
    __bf16* out = blockIdx.z ? WkT : WqT;
    const int x0 = blockIdx.x * 32;
    const int y0 = blockIdx.y * 32;
    for (int i = threadIdx.y; i < 32; i += 8)
        tile[i][threadIdx.x] = in[(size_t)(y0 + i) * 512 + (x0 + threadIdx.x)];
    __syncthreads();
    for (int i = threadIdx.y; i < 32; i += 8)
        out[(size_t)(x0 + i) * 512 + (y0 + threadIdx.x)] = (__bf16)tile[threadIdx.x][i];
}

// ---------------------------------------------------------------------------
// Projection GEMM (NT): Out = relu(X @ W + b), 128x128 tile, BK=32, async+swizzle.
// blockIdx.z selects (WqT,bq,qb) vs (WkT,bk,kb).
// ---------------------------------------------------------------------------
__global__ __launch_bounds__(256, 4) void proj_kernel(
    const __bf16* __restrict__ X,
    const __bf16* __restrict__ WqT, const __bf16* __restrict__ WkT,
    const float* __restrict__ bq, const float* __restrict__ bk,
    __bf16* __restrict__ qb, __bf16* __restrict__ kb)
{
    __shared__ __align__(16) ushort As[128 * 32];
    __shared__ __align__(16) ushort Bs[128 * 32];
    const __bf16* WT  = blockIdx.z ? WkT : WqT;
    const float* bias = blockIdx.z ? bk : bq;
    __bf16* Out       = blockIdx.z ? kb : qb;

    const int tid = threadIdx.x;
    const int wave = tid >> 6, lane = tid & 63, quad = lane >> 4, l16 = lane & 15;
    const int wm = (wave >> 1) * 64, wn = (wave & 1) * 64;
    const int m0 = blockIdx.y * 128, n0 = blockIdx.x * 128;
    const int sw = (quad ^ ((l16 >> 1) & 3)) * 8;   // swizzled chunk offset
    const int K = 512;

    f32x4 acc[4][4];
    f32x4 zero = {0.f, 0.f, 0.f, 0.f};
    for (int i = 0; i < 4; i++) for (int j = 0; j < 4; j++) acc[i][j] = zero;

    for (int k0 = 0; k0 < K; k0 += 32) {
        stage_async(As, X  + (size_t)m0 * K + k0, K, wave, lane);
        stage_async(Bs, WT + (size_t)n0 * K + k0, K, wave, lane);
        __syncthreads();
        bf16x8 af[4], bfr[4];
        for (int i = 0; i < 4; i++) af[i]  = *(bf16x8*)&As[(wm + i * 16 + l16) * 32 + sw];
        for (int j = 0; j < 4; j++) bfr[j] = *(bf16x8*)&Bs[(wn + j * 16 + l16) * 32 + sw];
        for (int i = 0; i < 4; i++)
            for (int j = 0; j < 4; j++)
                acc[i][j] = __builtin_amdgcn_mfma_f32_16x16x32_bf16(af[i], bfr[j], acc[i][j], 0, 0, 0);
        __syncthreads();
    }

    for (int i = 0; i < 4; i++) {
        const int row = m0 + wm + i * 16 + quad * 4;
        for (int j = 0; j < 4; j++) {
            const int col = n0 + wn + j * 16 + l16;
            const float bv = bias[col];
            for (int rr = 0; rr < 4; rr++) {
                float v = acc[i][j][rr] + bv;
                v = v > 0.f ? v : 0.f;
                Out[(size_t)(row + rr) * 512 + col] = (__bf16)v;
            }
        }
    }
}

// ---------------------------------------------------------------------------
// Scores GEMM (NT) + fused column-softmax tile stats + bf16 P output.
// ---------------------------------------------------------------------------
__global__ __launch_bounds__(256, 4) void scores_kernel(
    const __bf16* __restrict__ Q,   // [B*S, D] bf16
    const __bf16* __restrict__ Km,  // [B*S, D] bf16
    __bf16* __restrict__ P,         // [B, S, S] bf16
    float* __restrict__ Mp,         // [QSPLIT, B, S]
    float* __restrict__ Lp)         // [QSPLIT, B, S]
{
    __shared__ __align__(16) ushort As[128 * 32];
    __shared__ __align__(16) ushort Bs[128 * 32];
    const int b = blockIdx.z;
    const __bf16* A  = Q  + (size_t)b * Ss * Dd;
    const __bf16* Bp = Km + (size_t)b * Ss * Dd;
    __bf16* C = P + (size_t)b * Ss * Ss;

    const int tid = threadIdx.x;
    const int wave = tid >> 6, lane = tid & 63, quad = lane >> 4, l16 = lane & 15;
    const int wm = (wave >> 1) * 64, wn = (wave & 1) * 64;
    const int m0 = blockIdx.y * 128, n0 = blockIdx.x * 128;
    const int sw = (quad ^ ((l16 >> 1) & 3)) * 8;
    const float scale = 0.044194173824159216f; // 1/sqrt(512)

    f32x4 acc[4][4];
    f32x4 zero = {0.f, 0.f, 0.f, 0.f};
    for (int i = 0; i < 4; i++) for (int j = 0; j < 4; j++) acc[i][j] = zero;

    for (int k0 = 0; k0 < Dd; k0 += 32) {
        stage_async(As, A  + (size_t)m0 * Dd + k0, Dd, wave, lane);
        stage_async(Bs, Bp + (size_t)n0 * Dd + k0, Dd, wave, lane);
        __syncthreads();
        bf16x8 af[4], bfr[4];
        for (int i = 0; i < 4; i++) af[i]  = *(bf16x8*)&As[(wm + i * 16 + l16) * 32 + sw];
        for (int j = 0; j < 4; j++) bfr[j] = *(bf16x8*)&Bs[(wn + j * 16 + l16) * 32 + sw];
        for (int i = 0; i < 4; i++)
            for (int j = 0; j < 4; j++)
                acc[i][j] = __builtin_amdgcn_mfma_f32_16x16x32_bf16(af[i], bfr[j], acc[i][j], 0, 0, 0);
        __syncthreads();
    }

    // ---- tile column max (unscaled; scale>0 commutes with max) ----
    float* Ms = (float*)As;          // 256 f32 scratch (DMA drained by last barrier)
    float* Ls = ((float*)As) + 256;
    const int half = wave >> 1;
    float mj[4];
    for (int j = 0; j < 4; j++) {
        float m = -1e30f;
        for (int i = 0; i < 4; i++)
            for (int rr = 0; rr < 4; rr++)
                m = fmaxf(m, acc[i][j][rr]);
        m = fmaxf(m, __shfl_xor(m, 16));
        m = fmaxf(m, __shfl_xor(m, 32));
        mj[j] = m;
    }
    if (quad == 0)
        for (int j = 0; j < 4; j++) Ms[half * 128 + wn + j * 16 + l16] = mj[j];
    __syncthreads();
    float mt[4];
    for (int j = 0; j < 4; j++) {
        const int c = wn + j * 16 + l16;
        mt[j] = fmaxf(Ms[c], Ms[128 + c]);
    }
    // ---- exp + P store (bf16) + column sum ----
    float lj[4];
    for (int j = 0; j < 4; j++) {
        const int col = n0 + wn + j * 16 + l16;
        float l = 0.f;
        for (int i = 0; i < 4; i++) {
            const int row = m0 + wm + i * 16 + quad * 4;
            for (int rr = 0; rr < 4; rr++) {
                const float e = __expf((acc[i][j][rr] - mt[j]) * scale);
                C[(size_t)(row + rr) * Ss + col] = (__bf16)e;
                l += e;
            }
        }
        l += __shfl_xor(l, 16);
        l += __shfl_xor(l, 32);
        lj[j] = l;
    }
    if (quad == 0)
        for (int j = 0; j < 4; j++) Ls[half * 128 + wn + j * 16 + l16] = lj[j];
    __syncthreads();
    if (tid < 128) {
        const size_t o = ((size_t)blockIdx.y * Bb + b) * Ss + n0 + tid;
        Mp[o] = fmaxf(Ms[tid], Ms[128 + tid]) * scale;
        Lp[o] = Ls[tid] + Ls[128 + tid];
    }
}

// combine QSPLIT tile partials -> Mf (col max, scaled) and Li (1/sumexp)
__global__ void stats_combine(const float* __restrict__ Mp, const float* __restrict__ Lp,
                              float* __restrict__ Mf, float* __restrict__ Li) {
    const int idx = blockIdx.x * 256 + threadIdx.x;
    float m = -1e30f;
    for (int qy = 0; qy < QSPLIT; qy++) m = fmaxf(m, Mp[(size_t)qy * Bb * Ss + idx]);
    float l = 0.f;
    for (int qy = 0; qy < QSPLIT; qy++)
        l += Lp[(size_t)qy * Bb * Ss + idx] * __expf(Mp[(size_t)qy * Bb * Ss + idx] - m);
    Mf[idx] = m;
    Li[idx] = 1.0f / l;
}

// ---------------------------------------------------------------------------
// PV GEMM (NT), 128x128. attn = P * corr[k]; corr per block in LDS.
// A: register-staged (corr multiply) into swizzled LDS; B: async.
// Epilogue fuses residual from xb (bf16).
// ---------------------------------------------------------------------------
__global__ __launch_bounds__(256, 4) void pv_kernel(
    const __bf16* __restrict__ P,    // [B,S,S] bf16 tile-shifted exp scores
    const float* __restrict__ Mp,    // [QSPLIT,B,S]
    const float* __restrict__ Mf,    // [B,S]
    const float* __restrict__ Li,    // [B,S]
    const __bf16* __restrict__ XT,   // [B,E,S] bf16
    const __bf16* __restrict__ XB,   // [B,S,E] bf16 (residual)
    float* __restrict__ Out)         // [B,S,E] f32
{
    __shared__ __align__(16) ushort As[128 * 32];
    __shared__ __align__(16) ushort Bs[128 * 32];
    __shared__ float corr[Ss];       // 8 KB
    const int b = blockIdx.z;
    const int m0 = blockIdx.y * 128, n0 = blockIdx.x * 128;
    const int qy = blockIdx.y;
    const __bf16* A  = P  + (size_t)b * Ss * Ss;
    const __bf16* Bp = XT + (size_t)b * Ee * Ss;

    const int tid = threadIdx.x;
    const int wave = tid >> 6, lane = tid & 63, quad = lane >> 4, l16 = lane & 15;
    const int wm = (wave >> 1) * 64, wn = (wave & 1) * 64;
    const int sw = (quad ^ ((l16 >> 1) & 3)) * 8;
    const int r = tid >> 2, seg = (tid & 3) * 8;
    const int p8 = (((tid & 3) ^ ((r >> 1) & 3)) * 8);  // physical chunk (same for r and r+64)

    for (int k = tid; k < Ss; k += 256) {
        const float mp = Mp[((size_t)qy * Bb + b) * Ss + k];
        corr[k] = __expf(mp - Mf[(size_t)b * Ss + k]) * Li[(size_t)b * Ss + k];
    }
    __syncthreads();

    f32x4 acc[4][4];
    f32x4 zero = {0.f, 0.f, 0.f, 0.f};
    for (int i = 0; i < 4; i++) for (int j = 0; j < 4; j++) acc[i][j] = zero;

    for (int k0 = 0; k0 < Ss; k0 += 32) {
        float cv[8];
        #pragma unroll
        for (int t = 0; t < 8; t++) cv[t] = corr[k0 + seg + t];
        #pragma unroll
        for (int half = 0; half < 2; half++) {
            const int row = r + half * 64;
            const bf16x8 p = *(const bf16x8*)&A[(size_t)(m0 + row) * Ss + k0 + seg];
            bf16x8 o;
            #pragma unroll
            for (int t = 0; t < 8; t++) o[t] = (__bf16)((float)p[t] * cv[t]);
            *(bf16x8*)&As[row * 32 + p8] = o;
        }
        stage_async(Bs, Bp + (size_t)n0 * Ss + k0, Ss, wave, lane);
        __syncthreads();
        bf16x8 af[4], bfr[4];
        for (int i = 0; i < 4; i++) af[i]  = *(bf16x8*)&As[(wm + i * 16 + l16) * 32 + sw];
        for (int j = 0; j < 4; j++) bfr[j] = *(bf16x8*)&Bs[(wn + j * 16 + l16) * 32 + sw];
        for (int i = 0; i < 4; i++)
            for (int j = 0; j < 4; j++)
                acc[i][j] = __builtin_amdgcn_mfma_f32_16x16x32_bf16(af[i], bfr[j], acc[i][j], 0, 0, 0);
        __syncthreads();
    }

    for (int i = 0; i < 4; i++) {
        const int row = m0 + wm + i * 16 + quad * 4;
        for (int j = 0; j < 4; j++) {
            const int col = wn + j * 16 + l16 + n0;
            for (int rr = 0; rr < 4; rr++) {
                const size_t idx = ((size_t)b * Ss + row + rr) * Ee + col;
                Out[idx] = (float)XB[idx] + acc[i][j][rr];
            }
        }
    }
}

// ---------------------------------------------------------------------------
extern "C" void kernel_launch(void* const* d_in, const int* in_sizes, int n_in,
                              void* d_out, int out_size, void* d_ws, size_t ws_size,
                              hipStream_t stream) {
    const float* x  = (const float*)d_in[0];
    const float* Wq = (const float*)d_in[1];
    const float* bq = (const float*)d_in[2];
    const float* Wk = (const float*)d_in[3];
    const float* bk = (const float*)d_in[4];
    float* out = (float*)d_out;

    char* ws = (char*)d_ws;
    size_t off = 0;
    auto alloc = [&](size_t bytes) -> void* {
        void* p = ws + off;
        off += (bytes + 255) & ~(size_t)255;
        return p;
    };
    __bf16* P   = (__bf16*)alloc((size_t)Bb * Ss * Ss * 2);      // 64 MiB
    __bf16* xb  = (__bf16*)alloc((size_t)Bb * Ss * Ee * 2);      // 16 MiB
    __bf16* qb  = (__bf16*)alloc((size_t)Bb * Ss * Dd * 2);      // 16 MiB
    __bf16* kb  = (__bf16*)alloc((size_t)Bb * Ss * Dd * 2);      // 16 MiB
    __bf16* xT  = (__bf16*)alloc((size_t)Bb * Ee * Ss * 2);      // 16 MiB
    __bf16* WqT = (__bf16*)alloc((size_t)512 * 512 * 2);
    __bf16* WkT = (__bf16*)alloc((size_t)512 * 512 * 2);
    float*  Mp  = (float*)alloc((size_t)QSPLIT * Bb * Ss * 4);
    float*  Lp  = (float*)alloc((size_t)QSPLIT * Bb * Ss * 4);
    float*  Mf  = (float*)alloc((size_t)Bb * Ss * 4);
    float*  Li  = (float*)alloc((size_t)Bb * Ss * 4);
    if (off > ws_size) return;

    prep_x<<<dim3(16, 64, 8), dim3(32, 8), 0, stream>>>(x, xb, xT);
    transpose_w<<<dim3(16, 16, 2), dim3(32, 8), 0, stream>>>(Wq, Wk, WqT, WkT);

    // q = relu(x Wq + bq), k = relu(x Wk + bk)
    proj_kernel<<<dim3(4, 128, 2), 256, 0, stream>>>(xb, WqT, WkT, bq, bk, qb, kb);

    // P = exp(q k^T / sqrt(E) - m_tile) bf16 + tile stats
    scores_kernel<<<dim3(16, 16, 8), 256, 0, stream>>>(qb, kb, P, Mp, Lp);
    stats_combine<<<dim3(Bb * Ss / 256), 256, 0, stream>>>(Mp, Lp, Mf, Li);

    // out = xb + attn @ x
    pv_kernel<<<dim3(4, 16, 8), 256, 0, stream>>>(P, Mp, Mf, Li, xT, xb, out);
}

// Round 6
// 232.207 us; speedup vs baseline: 1.6496x; 1.0326x over previous
//
#include <hip/hip_runtime.h>
#include <hip/hip_bf16.h>
#include <math.h>

// Problem constants (B, S, E, D) for SA_Layer_45603962749650
#define Bb 8
#define Ss 2048
#define Ee 512
#define Dd 512
#define QSPLIT 16   // one partial per 128-row scores tile

typedef __bf16 bf16x8 __attribute__((ext_vector_type(8)));
typedef __bf16 bf16x4 __attribute__((ext_vector_type(4)));
typedef float f32x4 __attribute__((ext_vector_type(4)));

// ---------------------------------------------------------------------------
// Async-stage one 128x32 bf16 tile into swizzled LDS [128][32] (no padding).
// Chunk q (16B) of row r lives at physical chunk q ^ ((r>>1)&3).
// ---------------------------------------------------------------------------
__device__ __forceinline__ void stage_async(ushort* lds, const __bf16* gbase,
                                            int ldg, int wave, int lane) {
#pragma unroll
    for (int t = 0; t < 2; ++t) {
        const int idx = wave * 2 + t;               // 16-row chunk 0..7
        const int row = idx * 16 + (lane >> 2);
        const int q8  = (((lane & 3) ^ ((lane >> 3) & 3)) * 8);
        __builtin_amdgcn_global_load_lds(
            (const __attribute__((address_space(1))) void*)(gbase + (size_t)row * ldg + q8),
            (__attribute__((address_space(3))) void*)(lds + idx * 512),
            16, 0, 0);
    }
}

// ---------------------------------------------------------------------------
// prep_x: one pass over x. Writes xb = bf16(x) [B,S,E] and xT = bf16(x^T) [B,E,S]
// ---------------------------------------------------------------------------
__global__ void prep_x(const float* __restrict__ in, __bf16* __restrict__ xb,
                       __bf16* __restrict__ xT) {
    __shared__ float tile[32][33];
    const int b  = blockIdx.z;
    const int e0 = blockIdx.x * 32;
    const int s0 = blockIdx.y * 32;
    const float* ip = in + (size_t)b * Ss * Ee;
    __bf16* xbp = xb + (size_t)b * Ss * Ee;
    __bf16* xTp = xT + (size_t)b * Ee * Ss;
    for (int i = threadIdx.y; i < 32; i += 8) {
        const float v = ip[(size_t)(s0 + i) * Ee + e0 + threadIdx.x];
        tile[i][threadIdx.x] = v;
        xbp[(size_t)(s0 + i) * Ee + e0 + threadIdx.x] = (__bf16)v;
    }
    __syncthreads();
    for (int i = threadIdx.y; i < 32; i += 8)
        xTp[(size_t)(e0 + i) * Ss + s0 + threadIdx.x] = (__bf16)tile[threadIdx.x][i];
}

// ---------------------------------------------------------------------------
// Transpose 512x512: f32 in -> bf16 out. blockIdx.z selects Wq/Wk.
// ---------------------------------------------------------------------------
__global__ void transpose_w(const float* __restrict__ Wq, const float* __restrict__ Wk,
                            __bf16* __restrict__ WqT, __bf16* __restrict__ WkT) {
    __shared__ float tile[32][33];
    const float* in = blockIdx.z ? Wk : Wq;
    __bf16* out = blockIdx.z ? WkT : WqT;
    const int x0 = blockIdx.x * 32;
    const int y0 = blockIdx.y * 32;
    for (int i = threadIdx.y; i < 32; i += 8)
        tile[i][threadIdx.x] = in[(size_t)(y0 + i) * 512 + (x0 + threadIdx.x)];
    __syncthreads();
    for (int i = threadIdx.y; i < 32; i += 8)
        out[(size_t)(x0 + i) * 512 + (y0 + threadIdx.x)] = (__bf16)tile[threadIdx.x][i];
}

// ---------------------------------------------------------------------------
// Projection GEMM (NT): Out = relu(X @ W + b), 128x128 tile, BK=32, async+swizzle.
// ---------------------------------------------------------------------------
__global__ __launch_bounds__(256, 4) void proj_kernel(
    const __bf16* __restrict__ X,
    const __bf16* __restrict__ WqT, const __bf16* __restrict__ WkT,
    const float* __restrict__ bq, const float* __restrict__ bk,
    __bf16* __restrict__ qb, __bf16* __restrict__ kb)
{
    __shared__ __align__(16) ushort As[128 * 32];
    __shared__ __align__(16) ushort Bs[128 * 32];
    const __bf16* WT  = blockIdx.z ? WkT : WqT;
    const float* bias = blockIdx.z ? bk : bq;
    __bf16* Out       = blockIdx.z ? kb : qb;

    const int tid = threadIdx.x;
    const int wave = tid >> 6, lane = tid & 63, quad = lane >> 4, l16 = lane & 15;
    const int wm = (wave >> 1) * 64, wn = (wave & 1) * 64;
    const int m0 = blockIdx.y * 128, n0 = blockIdx.x * 128;
    const int sw = (quad ^ ((l16 >> 1) & 3)) * 8;
    const int K = 512;

    f32x4 acc[4][4];
    f32x4 zero = {0.f, 0.f, 0.f, 0.f};
    for (int i = 0; i < 4; i++) for (int j = 0; j < 4; j++) acc[i][j] = zero;

    for (int k0 = 0; k0 < K; k0 += 32) {
        stage_async(As, X  + (size_t)m0 * K + k0, K, wave, lane);
        stage_async(Bs, WT + (size_t)n0 * K + k0, K, wave, lane);
        __syncthreads();
        bf16x8 af[4], bfr[4];
        for (int i = 0; i < 4; i++) af[i]  = *(bf16x8*)&As[(wm + i * 16 + l16) * 32 + sw];
        for (int j = 0; j < 4; j++) bfr[j] = *(bf16x8*)&Bs[(wn + j * 16 + l16) * 32 + sw];
        for (int i = 0; i < 4; i++)
            for (int j = 0; j < 4; j++)
                acc[i][j] = __builtin_amdgcn_mfma_f32_16x16x32_bf16(af[i], bfr[j], acc[i][j], 0, 0, 0);
        __syncthreads();
    }

    for (int i = 0; i < 4; i++) {
        const int row = m0 + wm + i * 16 + quad * 4;
        for (int j = 0; j < 4; j++) {
            const int col = n0 + wn + j * 16 + l16;
            const float bv = bias[col];
            for (int rr = 0; rr < 4; rr++) {
                float v = acc[i][j][rr] + bv;
                v = v > 0.f ? v : 0.f;
                Out[(size_t)(row + rr) * 512 + col] = (__bf16)v;
            }
        }
    }
}

// ---------------------------------------------------------------------------
// Scores GEMM (NT) + fused column-softmax tile stats + bf16 P output.
// 1-D grid, XCD=batch swizzle: b = id&7, so (under round-robin dispatch)
// XCD b keeps qb/kb batch strips (2+2 MB) resident in its 4 MiB L2.
// ---------------------------------------------------------------------------
__global__ __launch_bounds__(256, 4) void scores_kernel(
    const __bf16* __restrict__ Q,   // [B*S, D] bf16
    const __bf16* __restrict__ Km,  // [B*S, D] bf16
    __bf16* __restrict__ P,         // [B, S, S] bf16
    float* __restrict__ Mp,         // [QSPLIT, B, S]
    float* __restrict__ Lp)         // [QSPLIT, B, S]
{
    __shared__ __align__(16) ushort As[128 * 32];
    __shared__ __align__(16) ushort Bs[128 * 32];
    const int id = blockIdx.x;            // 0..2047
    const int b = id & 7;
    const int rest = id >> 3;             // 0..255
    const int qy = rest >> 4;             // q tile 0..15
    const int m0 = qy * 128;
    const int n0 = (rest & 15) * 128;     // k tile
    const __bf16* A  = Q  + (size_t)b * Ss * Dd;
    const __bf16* Bp = Km + (size_t)b * Ss * Dd;
    __bf16* C = P + (size_t)b * Ss * Ss;

    const int tid = threadIdx.x;
    const int wave = tid >> 6, lane = tid & 63, quad = lane >> 4, l16 = lane & 15;
    const int wm = (wave >> 1) * 64, wn = (wave & 1) * 64;
    const int sw = (quad ^ ((l16 >> 1) & 3)) * 8;
    const float scale = 0.044194173824159216f; // 1/sqrt(512)

    f32x4 acc[4][4];
    f32x4 zero = {0.f, 0.f, 0.f, 0.f};
    for (int i = 0; i < 4; i++) for (int j = 0; j < 4; j++) acc[i][j] = zero;

    for (int k0 = 0; k0 < Dd; k0 += 32) {
        stage_async(As, A  + (size_t)m0 * Dd + k0, Dd, wave, lane);
        stage_async(Bs, Bp + (size_t)n0 * Dd + k0, Dd, wave, lane);
        __syncthreads();
        bf16x8 af[4], bfr[4];
        for (int i = 0; i < 4; i++) af[i]  = *(bf16x8*)&As[(wm + i * 16 + l16) * 32 + sw];
        for (int j = 0; j < 4; j++) bfr[j] = *(bf16x8*)&Bs[(wn + j * 16 + l16) * 32 + sw];
        for (int i = 0; i < 4; i++)
            for (int j = 0; j < 4; j++)
                acc[i][j] = __builtin_amdgcn_mfma_f32_16x16x32_bf16(af[i], bfr[j], acc[i][j], 0, 0, 0);
        __syncthreads();
    }

    // ---- tile column max (unscaled; scale>0 commutes with max) ----
    float* Ms = (float*)As;
    float* Ls = ((float*)As) + 256;
    const int half = wave >> 1;
    float mj[4];
    for (int j = 0; j < 4; j++) {
        float m = -1e30f;
        for (int i = 0; i < 4; i++)
            for (int rr = 0; rr < 4; rr++)
                m = fmaxf(m, acc[i][j][rr]);
        m = fmaxf(m, __shfl_xor(m, 16));
        m = fmaxf(m, __shfl_xor(m, 32));
        mj[j] = m;
    }
    if (quad == 0)
        for (int j = 0; j < 4; j++) Ms[half * 128 + wn + j * 16 + l16] = mj[j];
    __syncthreads();
    float mt[4];
    for (int j = 0; j < 4; j++) {
        const int c = wn + j * 16 + l16;
        mt[j] = fmaxf(Ms[c], Ms[128 + c]);
    }
    // ---- exp + P store (bf16) + column sum ----
    float lj[4];
    for (int j = 0; j < 4; j++) {
        const int col = n0 + wn + j * 16 + l16;
        float l = 0.f;
        for (int i = 0; i < 4; i++) {
            const int row = m0 + wm + i * 16 + quad * 4;
            for (int rr = 0; rr < 4; rr++) {
                const float e = __expf((acc[i][j][rr] - mt[j]) * scale);
                C[(size_t)(row + rr) * Ss + col] = (__bf16)e;
                l += e;
            }
        }
        l += __shfl_xor(l, 16);
        l += __shfl_xor(l, 32);
        lj[j] = l;
    }
    if (quad == 0)
        for (int j = 0; j < 4; j++) Ls[half * 128 + wn + j * 16 + l16] = lj[j];
    __syncthreads();
    if (tid < 128) {
        const size_t o = ((size_t)qy * Bb + b) * Ss + n0 + tid;
        Mp[o] = fmaxf(Ms[tid], Ms[128 + tid]) * scale;
        Lp[o] = Ls[tid] + Ls[128 + tid];
    }
}

// combine QSPLIT tile partials -> Mf (col max, scaled) and Li (1/sumexp)
__global__ void stats_combine(const float* __restrict__ Mp, const float* __restrict__ Lp,
                              float* __restrict__ Mf, float* __restrict__ Li) {
    const int idx = blockIdx.x * 256 + threadIdx.x;
    float m = -1e30f;
    for (int qy = 0; qy < QSPLIT; qy++) m = fmaxf(m, Mp[(size_t)qy * Bb * Ss + idx]);
    float l = 0.f;
    for (int qy = 0; qy < QSPLIT; qy++)
        l += Lp[(size_t)qy * Bb * Ss + idx] * __expf(Mp[(size_t)qy * Bb * Ss + idx] - m);
    Mf[idx] = m;
    Li[idx] = 1.0f / l;
}

// ---------------------------------------------------------------------------
// PV GEMM (NT), 128x128. attn = P * corr[k]; corr per block in LDS.
// 1-D grid, XCD=batch swizzle (b = id&7): xT batch strip (2 MB) L2-resident,
// P-strips (512 KB) read x4 while resident. A-path software-pipelined:
// next K-step's P loads issue between barrier1 and the MFMA block.
// ---------------------------------------------------------------------------
__global__ __launch_bounds__(256, 4) void pv_kernel(
    const __bf16* __restrict__ P,    // [B,S,S] bf16 tile-shifted exp scores
    const float* __restrict__ Mp,    // [QSPLIT,B,S]
    const float* __restrict__ Mf,    // [B,S]
    const float* __restrict__ Li,    // [B,S]
    const __bf16* __restrict__ XT,   // [B,E,S] bf16
    const __bf16* __restrict__ XB,   // [B,S,E] bf16 (residual)
    float* __restrict__ Out)         // [B,S,E] f32
{
    __shared__ __align__(16) ushort As[128 * 32];
    __shared__ __align__(16) ushort Bs[128 * 32];
    __shared__ float corr[Ss];       // 8 KB
    const int id = blockIdx.x;            // 0..511
    const int b = id & 7;
    const int rest = id >> 3;             // 0..63
    const int qy = rest >> 2;             // m tile 0..15
    const int m0 = qy * 128;
    const int n0 = (rest & 3) * 128;      // e tile
    const __bf16* A  = P  + (size_t)b * Ss * Ss;
    const __bf16* Bp = XT + (size_t)b * Ee * Ss;

    const int tid = threadIdx.x;
    const int wave = tid >> 6, lane = tid & 63, quad = lane >> 4, l16 = lane & 15;
    const int wm = (wave >> 1) * 64, wn = (wave & 1) * 64;
    const int sw = (quad ^ ((l16 >> 1) & 3)) * 8;
    const int r = tid >> 2, seg = (tid & 3) * 8;
    const int p8 = (((tid & 3) ^ ((r >> 1) & 3)) * 8);

    for (int k = tid; k < Ss; k += 256) {
        const float mp = Mp[((size_t)qy * Bb + b) * Ss + k];
        corr[k] = __expf(mp - Mf[(size_t)b * Ss + k]) * Li[(size_t)b * Ss + k];
    }
    __syncthreads();

    f32x4 acc[4][4];
    f32x4 zero = {0.f, 0.f, 0.f, 0.f};
    for (int i = 0; i < 4; i++) for (int j = 0; j < 4; j++) acc[i][j] = zero;

    const __bf16* Arow0 = A + (size_t)(m0 + r) * Ss;
    const __bf16* Arow1 = A + (size_t)(m0 + r + 64) * Ss;
    bf16x8 pr0 = *(const bf16x8*)&Arow0[seg];
    bf16x8 pr1 = *(const bf16x8*)&Arow1[seg];

    for (int k0 = 0; k0 < Ss; k0 += 32) {
        stage_async(Bs, Bp + (size_t)n0 * Ss + k0, Ss, wave, lane);
        float cv[8];
        #pragma unroll
        for (int t = 0; t < 8; t++) cv[t] = corr[k0 + seg + t];
        bf16x8 o0, o1;
        #pragma unroll
        for (int t = 0; t < 8; t++) o0[t] = (__bf16)((float)pr0[t] * cv[t]);
        #pragma unroll
        for (int t = 0; t < 8; t++) o1[t] = (__bf16)((float)pr1[t] * cv[t]);
        *(bf16x8*)&As[r * 32 + p8]        = o0;
        *(bf16x8*)&As[(r + 64) * 32 + p8] = o1;
        __syncthreads();
        bf16x8 af[4], bfr[4];
        for (int i = 0; i < 4; i++) af[i]  = *(bf16x8*)&As[(wm + i * 16 + l16) * 32 + sw];
        for (int j = 0; j < 4; j++) bfr[j] = *(bf16x8*)&Bs[(wn + j * 16 + l16) * 32 + sw];
        // prefetch next K-step's P (latency hides under the MFMA block)
        const int kn = (k0 + 32) & (Ss - 1);
        pr0 = *(const bf16x8*)&Arow0[kn + seg];
        pr1 = *(const bf16x8*)&Arow1[kn + seg];
        for (int i = 0; i < 4; i++)
            for (int j = 0; j < 4; j++)
                acc[i][j] = __builtin_amdgcn_mfma_f32_16x16x32_bf16(af[i], bfr[j], acc[i][j], 0, 0, 0);
        __syncthreads();
    }

    for (int i = 0; i < 4; i++) {
        const int row = m0 + wm + i * 16 + quad * 4;
        for (int j = 0; j < 4; j++) {
            const int col = wn + j * 16 + l16 + n0;
            for (int rr = 0; rr < 4; rr++) {
                const size_t idx = ((size_t)b * Ss + row + rr) * Ee + col;
                Out[idx] = (float)XB[idx] + acc[i][j][rr];
            }
        }
    }
}

// ---------------------------------------------------------------------------
extern "C" void kernel_launch(void* const* d_in, const int* in_sizes, int n_in,
                              void* d_out, int out_size, void* d_ws, size_t ws_size,
                              hipStream_t stream) {
    const float* x  = (const float*)d_in[0];
    const float* Wq = (const float*)d_in[1];
    const float* bq = (const float*)d_in[2];
    const float* Wk = (const float*)d_in[3];
    const float* bk = (const float*)d_in[4];
    float* out = (float*)d_out;

    char* ws = (char*)d_ws;
    size_t off = 0;
    auto alloc = [&](size_t bytes) -> void* {
        void* p = ws + off;
        off += (bytes + 255) & ~(size_t)255;
        return p;
    };
    __bf16* P   = (__bf16*)alloc((size_t)Bb * Ss * Ss * 2);      // 64 MiB
    __bf16* xb  = (__bf16*)alloc((size_t)Bb * Ss * Ee * 2);
    __bf16* qb  = (__bf16*)alloc((size_t)Bb * Ss * Dd * 2);
    __bf16* kb  = (__bf16*)alloc((size_t)Bb * Ss * Dd * 2);
    __bf16* xT  = (__bf16*)alloc((size_t)Bb * Ee * Ss * 2);
    __bf16* WqT = (__bf16*)alloc((size_t)512 * 512 * 2);
    __bf16* WkT = (__bf16*)alloc((size_t)512 * 512 * 2);
    float*  Mp  = (float*)alloc((size_t)QSPLIT * Bb * Ss * 4);
    float*  Lp  = (float*)alloc((size_t)QSPLIT * Bb * Ss * 4);
    float*  Mf  = (float*)alloc((size_t)Bb * Ss * 4);
    float*  Li  = (float*)alloc((size_t)Bb * Ss * 4);
    if (off > ws_size) return;

    prep_x<<<dim3(16, 64, 8), dim3(32, 8), 0, stream>>>(x, xb, xT);
    transpose_w<<<dim3(16, 16, 2), dim3(32, 8), 0, stream>>>(Wq, Wk, WqT, WkT);

    // q = relu(x Wq + bq), k = relu(x Wk + bk)
    proj_kernel<<<dim3(4, 128, 2), 256, 0, stream>>>(xb, WqT, WkT, bq, bk, qb, kb);

    // P = exp(q k^T / sqrt(E) - m_tile) bf16 + tile stats   (XCD=batch swizzle)
    scores_kernel<<<dim3(2048), 256, 0, stream>>>(qb, kb, P, Mp, Lp);
    stats_combine<<<dim3(Bb * Ss / 256), 256, 0, stream>>>(Mp, Lp, Mf, Li);

    // out = xb + attn @ x   (XCD=batch swizzle, pipelined A-path)
    pv_kernel<<<dim3(512), 256, 0, stream>>>(P, Mp, Mf, Li, xT, xb, out);
}

// Round 7
// 229.644 us; speedup vs baseline: 1.6680x; 1.0112x over previous
//
#include <hip/hip_runtime.h>
#include <hip/hip_bf16.h>
#include <math.h>

// Problem constants (B, S, E, D) for SA_Layer_45603962749650
#define Bb 8
#define Ss 2048
#define Ee 512
#define Dd 512
#define QSPLIT 16   // one partial per 128-row scores tile

typedef __bf16 bf16x8 __attribute__((ext_vector_type(8)));
typedef __bf16 bf16x4 __attribute__((ext_vector_type(4)));
typedef float f32x4 __attribute__((ext_vector_type(4)));

// ---------------------------------------------------------------------------
// Async-stage one 128x32 bf16 tile into swizzled LDS [128][32] (no padding).
// Chunk q (16B) of row r lives at physical chunk q ^ ((r>>1)&3).
// ---------------------------------------------------------------------------
__device__ __forceinline__ void stage_async(ushort* lds, const __bf16* gbase,
                                            int ldg, int wave, int lane) {
#pragma unroll
    for (int t = 0; t < 2; ++t) {
        const int idx = wave * 2 + t;               // 16-row chunk 0..7
        const int row = idx * 16 + (lane >> 2);
        const int q8  = (((lane & 3) ^ ((lane >> 3) & 3)) * 8);
        __builtin_amdgcn_global_load_lds(
            (const __attribute__((address_space(1))) void*)(gbase + (size_t)row * ldg + q8),
            (__attribute__((address_space(3))) void*)(lds + idx * 512),
            16, 0, 0);
    }
}

// ---------------------------------------------------------------------------
// prep_x: one pass over x. Writes xb = bf16(x) [B,S,E] and xT = bf16(x^T) [B,E,S]
// ---------------------------------------------------------------------------
__global__ void prep_x(const float* __restrict__ in, __bf16* __restrict__ xb,
                       __bf16* __restrict__ xT) {
    __shared__ float tile[32][33];
    const int b  = blockIdx.z;
    const int e0 = blockIdx.x * 32;
    const int s0 = blockIdx.y * 32;
    const float* ip = in + (size_t)b * Ss * Ee;
    __bf16* xbp = xb + (size_t)b * Ss * Ee;
    __bf16* xTp = xT + (size_t)b * Ee * Ss;
    for (int i = threadIdx.y; i < 32; i += 8) {
        const float v = ip[(size_t)(s0 + i) * Ee + e0 + threadIdx.x];
        tile[i][threadIdx.x] = v;
        xbp[(size_t)(s0 + i) * Ee + e0 + threadIdx.x] = (__bf16)v;
    }
    __syncthreads();
    for (int i = threadIdx.y; i < 32; i += 8)
        xTp[(size_t)(e0 + i) * Ss + s0 + threadIdx.x] = (__bf16)tile[threadIdx.x][i];
}

// ---------------------------------------------------------------------------
// Transpose 512x512: f32 in -> bf16 out. blockIdx.z selects Wq/Wk.
// ---------------------------------------------------------------------------
__global__ void transpose_w(const float* __restrict__ Wq, const float* __restrict__ Wk,
                            __bf16* __restrict__ WqT, __bf16* __restrict__ WkT) {
    __shared__ float tile[32][33];
    const float* in = blockIdx.z ? Wk : Wq;
    __bf16* out = blockIdx.z ? WkT : WqT;
    const int x0 = blockIdx.x * 32;
    const int y0 = blockIdx.y * 32;
    for (int i = threadIdx.y; i < 32; i += 8)
        tile[i][threadIdx.x] = in[(size_t)(y0 + i) * 512 + (x0 + threadIdx.x)];
    __syncthreads();
    for (int i = threadIdx.y; i < 32; i += 8)
        out[(size_t)(x0 + i) * 512 + (y0 + threadIdx.x)] = (__bf16)tile[threadIdx.x][i];
}

// ---------------------------------------------------------------------------
// Projection GEMM (NT): Out = relu(X @ W + b), 128x128 tile, BK=32, async+swizzle.
// ---------------------------------------------------------------------------
__global__ __launch_bounds__(256, 4) void proj_kernel(
    const __bf16* __restrict__ X,
    const __bf16* __restrict__ WqT, const __bf16* __restrict__ WkT,
    const float* __restrict__ bq, const float* __restrict__ bk,
    __bf16* __restrict__ qb, __bf16* __restrict__ kb)
{
    __shared__ __align__(16) ushort As[128 * 32];
    __shared__ __align__(16) ushort Bs[128 * 32];
    const __bf16* WT  = blockIdx.z ? WkT : WqT;
    const float* bias = blockIdx.z ? bk : bq;
    __bf16* Out       = blockIdx.z ? kb : qb;

    const int tid = threadIdx.x;
    const int wave = tid >> 6, lane = tid & 63, quad = lane >> 4, l16 = lane & 15;
    const int wm = (wave >> 1) * 64, wn = (wave & 1) * 64;
    const int m0 = blockIdx.y * 128, n0 = blockIdx.x * 128;
    const int sw = (quad ^ ((l16 >> 1) & 3)) * 8;
    const int K = 512;

    f32x4 acc[4][4];
    f32x4 zero = {0.f, 0.f, 0.f, 0.f};
    for (int i = 0; i < 4; i++) for (int j = 0; j < 4; j++) acc[i][j] = zero;

    for (int k0 = 0; k0 < K; k0 += 32) {
        stage_async(As, X  + (size_t)m0 * K + k0, K, wave, lane);
        stage_async(Bs, WT + (size_t)n0 * K + k0, K, wave, lane);
        __syncthreads();
        bf16x8 af[4], bfr[4];
        for (int i = 0; i < 4; i++) af[i]  = *(bf16x8*)&As[(wm + i * 16 + l16) * 32 + sw];
        for (int j = 0; j < 4; j++) bfr[j] = *(bf16x8*)&Bs[(wn + j * 16 + l16) * 32 + sw];
        for (int i = 0; i < 4; i++)
            for (int j = 0; j < 4; j++)
                acc[i][j] = __builtin_amdgcn_mfma_f32_16x16x32_bf16(af[i], bfr[j], acc[i][j], 0, 0, 0);
        __syncthreads();
    }

    for (int i = 0; i < 4; i++) {
        const int row = m0 + wm + i * 16 + quad * 4;
        for (int j = 0; j < 4; j++) {
            const int col = n0 + wn + j * 16 + l16;
            const float bv = bias[col];
            for (int rr = 0; rr < 4; rr++) {
                float v = acc[i][j][rr] + bv;
                v = v > 0.f ? v : 0.f;
                Out[(size_t)(row + rr) * 512 + col] = (__bf16)v;
            }
        }
    }
}

// ---------------------------------------------------------------------------
// Scores GEMM (NT) + fused column-softmax tile stats + bf16 P output.
// 1-D grid, XCD=batch swizzle: b = id&7 keeps qb/kb batch strips L2-resident.
// ---------------------------------------------------------------------------
__global__ __launch_bounds__(256, 4) void scores_kernel(
    const __bf16* __restrict__ Q,   // [B*S, D] bf16
    const __bf16* __restrict__ Km,  // [B*S, D] bf16
    __bf16* __restrict__ P,         // [B, S, S] bf16
    float* __restrict__ Mp,         // [QSPLIT, B, S]
    float* __restrict__ Lp)         // [QSPLIT, B, S]
{
    __shared__ __align__(16) ushort As[128 * 32];
    __shared__ __align__(16) ushort Bs[128 * 32];
    const int id = blockIdx.x;            // 0..2047
    const int b = id & 7;
    const int rest = id >> 3;             // 0..255
    const int qy = rest >> 4;             // q tile 0..15
    const int m0 = qy * 128;
    const int n0 = (rest & 15) * 128;     // k tile
    const __bf16* A  = Q  + (size_t)b * Ss * Dd;
    const __bf16* Bp = Km + (size_t)b * Ss * Dd;
    __bf16* C = P + (size_t)b * Ss * Ss;

    const int tid = threadIdx.x;
    const int wave = tid >> 6, lane = tid & 63, quad = lane >> 4, l16 = lane & 15;
    const int wm = (wave >> 1) * 64, wn = (wave & 1) * 64;
    const int sw = (quad ^ ((l16 >> 1) & 3)) * 8;
    const float scale = 0.044194173824159216f; // 1/sqrt(512)

    f32x4 acc[4][4];
    f32x4 zero = {0.f, 0.f, 0.f, 0.f};
    for (int i = 0; i < 4; i++) for (int j = 0; j < 4; j++) acc[i][j] = zero;

    for (int k0 = 0; k0 < Dd; k0 += 32) {
        stage_async(As, A  + (size_t)m0 * Dd + k0, Dd, wave, lane);
        stage_async(Bs, Bp + (size_t)n0 * Dd + k0, Dd, wave, lane);
        __syncthreads();
        bf16x8 af[4], bfr[4];
        for (int i = 0; i < 4; i++) af[i]  = *(bf16x8*)&As[(wm + i * 16 + l16) * 32 + sw];
        for (int j = 0; j < 4; j++) bfr[j] = *(bf16x8*)&Bs[(wn + j * 16 + l16) * 32 + sw];
        for (int i = 0; i < 4; i++)
            for (int j = 0; j < 4; j++)
                acc[i][j] = __builtin_amdgcn_mfma_f32_16x16x32_bf16(af[i], bfr[j], acc[i][j], 0, 0, 0);
        __syncthreads();
    }

    // ---- tile column max (unscaled; scale>0 commutes with max) ----
    float* Ms = (float*)As;
    float* Ls = ((float*)As) + 256;
    const int half = wave >> 1;
    float mj[4];
    for (int j = 0; j < 4; j++) {
        float m = -1e30f;
        for (int i = 0; i < 4; i++)
            for (int rr = 0; rr < 4; rr++)
                m = fmaxf(m, acc[i][j][rr]);
        m = fmaxf(m, __shfl_xor(m, 16));
        m = fmaxf(m, __shfl_xor(m, 32));
        mj[j] = m;
    }
    if (quad == 0)
        for (int j = 0; j < 4; j++) Ms[half * 128 + wn + j * 16 + l16] = mj[j];
    __syncthreads();
    float mt[4];
    for (int j = 0; j < 4; j++) {
        const int c = wn + j * 16 + l16;
        mt[j] = fmaxf(Ms[c], Ms[128 + c]);
    }
    // ---- exp + P store (bf16) + column sum ----
    float lj[4];
    for (int j = 0; j < 4; j++) {
        const int col = n0 + wn + j * 16 + l16;
        float l = 0.f;
        for (int i = 0; i < 4; i++) {
            const int row = m0 + wm + i * 16 + quad * 4;
            for (int rr = 0; rr < 4; rr++) {
                const float e = __expf((acc[i][j][rr] - mt[j]) * scale);
                C[(size_t)(row + rr) * Ss + col] = (__bf16)e;
                l += e;
            }
        }
        l += __shfl_xor(l, 16);
        l += __shfl_xor(l, 32);
        lj[j] = l;
    }
    if (quad == 0)
        for (int j = 0; j < 4; j++) Ls[half * 128 + wn + j * 16 + l16] = lj[j];
    __syncthreads();
    if (tid < 128) {
        const size_t o = ((size_t)qy * Bb + b) * Ss + n0 + tid;
        Mp[o] = fmaxf(Ms[tid], Ms[128 + tid]) * scale;
        Lp[o] = Ls[tid] + Ls[128 + tid];
    }
}

// combine QSPLIT tile partials -> Mf (col max, scaled) and Li (1/sumexp)
__global__ void stats_combine(const float* __restrict__ Mp, const float* __restrict__ Lp,
                              float* __restrict__ Mf, float* __restrict__ Li) {
    const int idx = blockIdx.x * 256 + threadIdx.x;
    float m = -1e30f;
    for (int qy = 0; qy < QSPLIT; qy++) m = fmaxf(m, Mp[(size_t)qy * Bb * Ss + idx]);
    float l = 0.f;
    for (int qy = 0; qy < QSPLIT; qy++)
        l += Lp[(size_t)qy * Bb * Ss + idx] * __expf(Mp[(size_t)qy * Bb * Ss + idx] - m);
    Mf[idx] = m;
    Li[idx] = 1.0f / l;
}

// ---------------------------------------------------------------------------
// PV GEMM (NT), 64x128 tiles -> 1024 blocks -> 4 blocks/CU (16 waves/CU).
// attn = P * corr[k]; corr per block in LDS. XCD=batch swizzle (b = id&7).
// Wave w covers N cols [w*32, w*32+32); A-path register-staged + prefetched.
// ---------------------------------------------------------------------------
__global__ __launch_bounds__(256, 4) void pv_kernel(
    const __bf16* __restrict__ P,    // [B,S,S] bf16 tile-shifted exp scores
    const float* __restrict__ Mp,    // [QSPLIT,B,S]
    const float* __restrict__ Mf,    // [B,S]
    const float* __restrict__ Li,    // [B,S]
    const __bf16* __restrict__ XT,   // [B,E,S] bf16
    const __bf16* __restrict__ XB,   // [B,S,E] bf16 (residual)
    float* __restrict__ Out)         // [B,S,E] f32
{
    __shared__ __align__(16) ushort As[64 * 32];    // 4 KB
    __shared__ __align__(16) ushort Bs[128 * 32];   // 8 KB
    __shared__ float corr[Ss];                      // 8 KB
    const int id = blockIdx.x;            // 0..1023
    const int b = id & 7;
    const int rest = id >> 3;             // 0..127
    const int m0 = (rest >> 2) * 64;      // m tile 0..31 (64 rows)
    const int n0 = (rest & 3) * 128;      // e tile
    const int qy = m0 >> 7;               // 128-row scores-tile index for Mp
    const __bf16* A  = P  + (size_t)b * Ss * Ss;
    const __bf16* Bp = XT + (size_t)b * Ee * Ss;

    const int tid = threadIdx.x;
    const int wave = tid >> 6, lane = tid & 63, quad = lane >> 4, l16 = lane & 15;
    const int wn = wave * 32;
    const int sw = (quad ^ ((l16 >> 1) & 3)) * 8;
    const int r = tid >> 2, seg = (tid & 3) * 8;          // A stage: 64 rows x 4 thr
    const int p8 = (((tid & 3) ^ ((r >> 1) & 3)) * 8);

    for (int k = tid; k < Ss; k += 256) {
        const float mp = Mp[((size_t)qy * Bb + b) * Ss + k];
        corr[k] = __expf(mp - Mf[(size_t)b * Ss + k]) * Li[(size_t)b * Ss + k];
    }
    __syncthreads();

    f32x4 acc[4][2];
    f32x4 zero = {0.f, 0.f, 0.f, 0.f};
    for (int i = 0; i < 4; i++) for (int j = 0; j < 2; j++) acc[i][j] = zero;

    const __bf16* Arow = A + (size_t)(m0 + r) * Ss;
    bf16x8 pr = *(const bf16x8*)&Arow[seg];

    for (int k0 = 0; k0 < Ss; k0 += 32) {
        stage_async(Bs, Bp + (size_t)n0 * Ss + k0, Ss, wave, lane);
        float cv[8];
        #pragma unroll
        for (int t = 0; t < 8; t++) cv[t] = corr[k0 + seg + t];
        bf16x8 o;
        #pragma unroll
        for (int t = 0; t < 8; t++) o[t] = (__bf16)((float)pr[t] * cv[t]);
        *(bf16x8*)&As[r * 32 + p8] = o;
        __syncthreads();
        bf16x8 af[4], bfr[2];
        for (int i = 0; i < 4; i++) af[i]  = *(bf16x8*)&As[(i * 16 + l16) * 32 + sw];
        for (int j = 0; j < 2; j++) bfr[j] = *(bf16x8*)&Bs[(wn + j * 16 + l16) * 32 + sw];
        // prefetch next K-step's P (latency hides under the MFMA block)
        const int kn = (k0 + 32) & (Ss - 1);
        pr = *(const bf16x8*)&Arow[kn + seg];
        for (int i = 0; i < 4; i++)
            for (int j = 0; j < 2; j++)
                acc[i][j] = __builtin_amdgcn_mfma_f32_16x16x32_bf16(af[i], bfr[j], acc[i][j], 0, 0, 0);
        __syncthreads();
    }

    for (int i = 0; i < 4; i++) {
        const int row = m0 + i * 16 + quad * 4;
        for (int j = 0; j < 2; j++) {
            const int col = n0 + wn + j * 16 + l16;
            for (int rr = 0; rr < 4; rr++) {
                const size_t idx = ((size_t)b * Ss + row + rr) * Ee + col;
                Out[idx] = (float)XB[idx] + acc[i][j][rr];
            }
        }
    }
}

// ---------------------------------------------------------------------------
extern "C" void kernel_launch(void* const* d_in, const int* in_sizes, int n_in,
                              void* d_out, int out_size, void* d_ws, size_t ws_size,
                              hipStream_t stream) {
    const float* x  = (const float*)d_in[0];
    const float* Wq = (const float*)d_in[1];
    const float* bq = (const float*)d_in[2];
    const float* Wk = (const float*)d_in[3];
    const float* bk = (const float*)d_in[4];
    float* out = (float*)d_out;

    char* ws = (char*)d_ws;
    size_t off = 0;
    auto alloc = [&](size_t bytes) -> void* {
        void* p = ws + off;
        off += (bytes + 255) & ~(size_t)255;
        return p;
    };
    __bf16* P   = (__bf16*)alloc((size_t)Bb * Ss * Ss * 2);      // 64 MiB
    __bf16* xb  = (__bf16*)alloc((size_t)Bb * Ss * Ee * 2);
    __bf16* qb  = (__bf16*)alloc((size_t)Bb * Ss * Dd * 2);
    __bf16* kb  = (__bf16*)alloc((size_t)Bb * Ss * Dd * 2);
    __bf16* xT  = (__bf16*)alloc((size_t)Bb * Ee * Ss * 2);
    __bf16* WqT = (__bf16*)alloc((size_t)512 * 512 * 2);
    __bf16* WkT = (__bf16*)alloc((size_t)512 * 512 * 2);
    float*  Mp  = (float*)alloc((size_t)QSPLIT * Bb * Ss * 4);
    float*  Lp  = (float*)alloc((size_t)QSPLIT * Bb * Ss * 4);
    float*  Mf  = (float*)alloc((size_t)Bb * Ss * 4);
    float*  Li  = (float*)alloc((size_t)Bb * Ss * 4);
    if (off > ws_size) return;

    prep_x<<<dim3(16, 64, 8), dim3(32, 8), 0, stream>>>(x, xb, xT);
    transpose_w<<<dim3(16, 16, 2), dim3(32, 8), 0, stream>>>(Wq, Wk, WqT, WkT);

    // q = relu(x Wq + bq), k = relu(x Wk + bk)
    proj_kernel<<<dim3(4, 128, 2), 256, 0, stream>>>(xb, WqT, WkT, bq, bk, qb, kb);

    // P = exp(q k^T / sqrt(E) - m_tile) bf16 + tile stats   (XCD=batch swizzle)
    scores_kernel<<<dim3(2048), 256, 0, stream>>>(qb, kb, P, Mp, Lp);
    stats_combine<<<dim3(Bb * Ss / 256), 256, 0, stream>>>(Mp, Lp, Mf, Li);

    // out = xb + attn @ x   (XCD=batch swizzle, 64x128 tiles, 1024 blocks)
    pv_kernel<<<dim3(1024), 256, 0, stream>>>(P, Mp, Mf, Li, xT, xb, out);
}